// Round 1
// baseline (1051.392 us; speedup 1.0000x reference)
//
#include <hip/hip_runtime.h>
#include <stdint.h>

#define DIM   512
#define QKD   128
#define HID   1024
#define HID2  2048
#define OUTD  8
#define BATCH 4
#define SEQ   4096
#define ROWS  (BATCH*SEQ)   // 16384
#define LN_EPS 1e-5f

typedef unsigned short u16;
typedef __bf16 bf16x8 __attribute__((ext_vector_type(8)));
typedef float  f32x4  __attribute__((ext_vector_type(4)));

// ---------- helpers ----------
__device__ inline u16 f2bf(float f){
    uint32_t u = __builtin_bit_cast(uint32_t, f);
    u += 0x7FFFu + ((u >> 16) & 1u);   // RNE
    return (u16)(u >> 16);
}
__device__ inline float bf2f(u16 h){
    uint32_t u = ((uint32_t)h) << 16;
    return __builtin_bit_cast(float, u);
}
__device__ inline void split_bf16(float x, u16 &hi, u16 &lo){
    hi = f2bf(x);
    float r = x - bf2f(hi);
    lo = f2bf(r);
}
__device__ inline bf16x8 ld_frag(const u16* p){
    uint4 r = *reinterpret_cast<const uint4*>(p);
    return __builtin_bit_cast(bf16x8, r);
}
__device__ inline f32x4 mfma16(bf16x8 a, bf16x8 b, f32x4 c){
    return __builtin_amdgcn_mfma_f32_16x16x32_bf16(a, b, c, 0, 0, 0);
}
__device__ inline float silu(float x){ return x / (1.f + expf(-x)); }

// ---------- P: split + transpose weights ----------
__global__ void prep_split(const float* __restrict__ Wh, const float* __restrict__ Wqk,
                           u16* whth, u16* whtl, u16* wqkth, u16* wqktl){
    int tid = blockIdx.x*256 + threadIdx.x;
    const int NWH = HID2*DIM;            // 1048576
    if (tid < NWH){
        int k = tid & (DIM-1);
        int n = tid >> 9;
        float w = Wh[(size_t)k*HID2 + n];
        u16 h,l; split_bf16(w,h,l);
        whth[tid]=h; whtl[tid]=l;
    } else {
        int t2 = tid - NWH;
        if (t2 < QKD*DIM){
            int k = t2 & (DIM-1);
            int n = t2 >> 9;
            float w = Wqk[(size_t)k*QKD + n];
            u16 h,l; split_bf16(w,h,l);
            wqkth[t2]=h; wqktl[t2]=l;
        }
    }
}

// ---------- K1: layernorm -> split bf16 ----------
__global__ __launch_bounds__(256) void ln_kernel(const float* __restrict__ x,
                                                 const float* __restrict__ g,
                                                 const float* __restrict__ b,
                                                 u16* nh, u16* nl){
    int wave = threadIdx.x >> 6, lane = threadIdx.x & 63;
    int row  = blockIdx.x*4 + wave;
    const float* xr = x + (size_t)row*DIM;
    float4 v0 = *(const float4*)(xr + lane*8);
    float4 v1 = *(const float4*)(xr + lane*8 + 4);
    float xs[8] = {v0.x,v0.y,v0.z,v0.w,v1.x,v1.y,v1.z,v1.w};
    float s = 0.f, q = 0.f;
    #pragma unroll
    for (int i=0;i<8;++i){ s += xs[i]; q += xs[i]*xs[i]; }
    #pragma unroll
    for (int m=1;m<64;m<<=1){ s += __shfl_xor(s,m,64); q += __shfl_xor(q,m,64); }
    float mean = s * (1.f/DIM);
    float var  = q * (1.f/DIM) - mean*mean;
    float rstd = rsqrtf(var + LN_EPS);
    float4 g0 = *(const float4*)(g + lane*8);
    float4 g1 = *(const float4*)(g + lane*8 + 4);
    float4 b0 = *(const float4*)(b + lane*8);
    float4 b1 = *(const float4*)(b + lane*8 + 4);
    float gs[8] = {g0.x,g0.y,g0.z,g0.w,g1.x,g1.y,g1.z,g1.w};
    float bs[8] = {b0.x,b0.y,b0.z,b0.w,b1.x,b1.y,b1.z,b1.w};
    u16 hh[8], ll[8];
    #pragma unroll
    for (int i=0;i<8;++i){
        float nv = (xs[i]-mean)*rstd*gs[i] + bs[i];
        split_bf16(nv, hh[i], ll[i]);
    }
    size_t o = (size_t)row*DIM + lane*8;
    *(uint4*)(nh + o) = *(uint4*)hh;
    *(uint4*)(nl + o) = *(uint4*)ll;
}

// ---------- K2: hidden = silu(n @ Wh + bh) -> v^T split + gate ----------
__global__ __launch_bounds__(256,2) void gemm_h(
        const u16* __restrict__ nh, const u16* __restrict__ nl,
        const u16* __restrict__ bth, const u16* __restrict__ btl,
        const float* __restrict__ bh,
        u16* vth, u16* vtl, float* gate){
    __shared__ __align__(16) u16 At[2][128][40];
    __shared__ __align__(16) u16 Bt[2][128][40];
    int n0 = blockIdx.x * 128;
    int m0 = blockIdx.y * 128;
    int wave = threadIdx.x>>6, lane = threadIdx.x&63;
    int wr = wave>>1, wc = wave&1;
    f32x4 acc[4][4] = {};
    for (int ks=0; ks<16; ++ks){
        #pragma unroll
        for (int r=0;r<2;++r){
            int idx = r*256 + threadIdx.x;   // 0..511
            int row = idx>>2, ch = idx&3;
            size_t ga = (size_t)(m0+row)*DIM + ks*32 + ch*8;
            size_t gb = (size_t)(n0+row)*DIM + ks*32 + ch*8;
            *(uint4*)&At[0][row][ch*8] = *(const uint4*)(nh + ga);
            *(uint4*)&At[1][row][ch*8] = *(const uint4*)(nl + ga);
            *(uint4*)&Bt[0][row][ch*8] = *(const uint4*)(bth + gb);
            *(uint4*)&Bt[1][row][ch*8] = *(const uint4*)(btl + gb);
        }
        __syncthreads();
        bf16x8 Ah[4], Al[4];
        #pragma unroll
        for (int rf=0;rf<4;++rf){
            Ah[rf] = ld_frag(&At[0][wr*64 + rf*16 + (lane&15)][(lane>>4)*8]);
            Al[rf] = ld_frag(&At[1][wr*64 + rf*16 + (lane&15)][(lane>>4)*8]);
        }
        #pragma unroll
        for (int cf=0;cf<4;++cf){
            bf16x8 Bh = ld_frag(&Bt[0][wc*64 + cf*16 + (lane&15)][(lane>>4)*8]);
            bf16x8 Bl = ld_frag(&Bt[1][wc*64 + cf*16 + (lane&15)][(lane>>4)*8]);
            #pragma unroll
            for (int rf=0;rf<4;++rf){
                acc[rf][cf] = mfma16(Ah[rf], Bh, acc[rf][cf]);
                acc[rf][cf] = mfma16(Ah[rf], Bl, acc[rf][cf]);
                acc[rf][cf] = mfma16(Al[rf], Bh, acc[rf][cf]);
            }
        }
        __syncthreads();
    }
    #pragma unroll
    for (int rf=0;rf<4;++rf){
        #pragma unroll
        for (int cf=0;cf<4;++cf){
            #pragma unroll
            for (int r=0;r<4;++r){
                int row = m0 + wr*64 + rf*16 + (lane>>4)*4 + r;
                int col = n0 + wc*64 + cf*16 + (lane&15);
                float h = acc[rf][cf][r] + bh[col];
                float s = silu(h);
                if (col < HID){
                    int b = row >> 12, i = row & (SEQ-1);
                    u16 sh, sl; split_bf16(s, sh, sl);
                    size_t o = ((size_t)b*HID + col)*SEQ + i;
                    vth[o] = sh; vtl[o] = sl;
                } else {
                    gate[(size_t)row*HID + (col - HID)] = s;
                }
            }
        }
    }
}

// ---------- K3: Z = silu(n @ Wqk + bqk); q,k = Z*gamma+beta -> split ----------
__global__ __launch_bounds__(256,2) void gemm_qk(
        const u16* __restrict__ nh, const u16* __restrict__ nl,
        const u16* __restrict__ bth, const u16* __restrict__ btl,
        const float* __restrict__ bqk, const float* __restrict__ gamma,
        const float* __restrict__ beta,
        u16* qh, u16* ql, u16* kh, u16* kl){
    __shared__ __align__(16) u16 At[2][128][40];
    __shared__ __align__(16) u16 Bt[2][128][40];
    int m0 = blockIdx.x * 128;
    int wave = threadIdx.x>>6, lane = threadIdx.x&63;
    int wr = wave>>1, wc = wave&1;
    f32x4 acc[4][4] = {};
    for (int ks=0; ks<16; ++ks){
        #pragma unroll
        for (int r=0;r<2;++r){
            int idx = r*256 + threadIdx.x;
            int row = idx>>2, ch = idx&3;
            size_t ga = (size_t)(m0+row)*DIM + ks*32 + ch*8;
            size_t gb = (size_t)row*DIM + ks*32 + ch*8;   // n0 = 0, N=128
            *(uint4*)&At[0][row][ch*8] = *(const uint4*)(nh + ga);
            *(uint4*)&At[1][row][ch*8] = *(const uint4*)(nl + ga);
            *(uint4*)&Bt[0][row][ch*8] = *(const uint4*)(bth + gb);
            *(uint4*)&Bt[1][row][ch*8] = *(const uint4*)(btl + gb);
        }
        __syncthreads();
        bf16x8 Ah[4], Al[4];
        #pragma unroll
        for (int rf=0;rf<4;++rf){
            Ah[rf] = ld_frag(&At[0][wr*64 + rf*16 + (lane&15)][(lane>>4)*8]);
            Al[rf] = ld_frag(&At[1][wr*64 + rf*16 + (lane&15)][(lane>>4)*8]);
        }
        #pragma unroll
        for (int cf=0;cf<4;++cf){
            bf16x8 Bh = ld_frag(&Bt[0][wc*64 + cf*16 + (lane&15)][(lane>>4)*8]);
            bf16x8 Bl = ld_frag(&Bt[1][wc*64 + cf*16 + (lane&15)][(lane>>4)*8]);
            #pragma unroll
            for (int rf=0;rf<4;++rf){
                acc[rf][cf] = mfma16(Ah[rf], Bh, acc[rf][cf]);
                acc[rf][cf] = mfma16(Ah[rf], Bl, acc[rf][cf]);
                acc[rf][cf] = mfma16(Al[rf], Bh, acc[rf][cf]);
            }
        }
        __syncthreads();
    }
    #pragma unroll
    for (int rf=0;rf<4;++rf){
        #pragma unroll
        for (int cf=0;cf<4;++cf){
            #pragma unroll
            for (int r=0;r<4;++r){
                int row = m0 + wr*64 + rf*16 + (lane>>4)*4 + r;
                int col = wc*64 + cf*16 + (lane&15);
                float z = silu(acc[rf][cf][r] + bqk[col]);
                float qv = z*gamma[col]       + beta[col];
                float kv = z*gamma[QKD + col] + beta[QKD + col];
                size_t o = (size_t)row*QKD + col;
                u16 h_, l_;
                split_bf16(qv, h_, l_); qh[o]=h_; ql[o]=l_;
                split_bf16(kv, h_, l_); kh[o]=h_; kl[o]=l_;
            }
        }
    }
}

// ---------- K4: fused squared-relu attention ----------
// grid = 256 blocks (1/CU), 512 threads (8 waves). Each block: batch + 64-row q tile.
// Each wave owns a 128-wide d slice of V. gate buffer is overwritten with V*gate/n^2.
__global__ __launch_bounds__(512,2) void attn(
        const u16* __restrict__ qh_, const u16* __restrict__ ql_,
        const u16* __restrict__ kh_, const u16* __restrict__ kl_,
        const u16* __restrict__ vth, const u16* __restrict__ vtl,
        float* gate){
    __shared__ __align__(16) u16 Q[2][64][136];
    __shared__ __align__(16) u16 A[2][64][72];
    int bid   = blockIdx.x;
    int batch = (bid & 7) >> 1;                    // 2 XCDs per batch (L2 locality)
    int qt    = (bid & 1) | ((bid >> 3) << 1);
    int i0    = qt * 64;
    int wave  = threadIdx.x >> 6, lane = threadIdx.x & 63;

    // stage q tile (hi/lo) into LDS, padded rows
    {
        const u16* srcs[2] = {qh_, ql_};
        #pragma unroll
        for (int h=0;h<2;++h){
            #pragma unroll
            for (int r=0;r<2;++r){
                int idx = r*512 + threadIdx.x;     // 0..1023
                int row = idx >> 4, ch = idx & 15;
                *(uint4*)&Q[h][row][ch*8] =
                    *(const uint4*)(srcs[h] + ((size_t)(batch*SEQ + i0 + row))*QKD + ch*8);
            }
        }
    }
    __syncthreads();

    f32x4 acc[4][8] = {};
    int si = wave >> 1, sjb = (wave & 1) * 2;

    for (int kt=0; kt<64; ++kt){
        // ---- S = q.k^T (raw, unscaled) ----
        f32x4 sacc[2] = {};
        #pragma unroll
        for (int kstep=0;kstep<4;++kstep){
            bf16x8 qa = ld_frag(&Q[0][si*16 + (lane&15)][((lane>>4) + kstep*4)*8]);
            bf16x8 qb = ld_frag(&Q[1][si*16 + (lane&15)][((lane>>4) + kstep*4)*8]);
            #pragma unroll
            for (int t=0;t<2;++t){
                int j = batch*SEQ + kt*64 + (sjb+t)*16 + (lane&15);
                size_t ko = (size_t)j*QKD + kstep*32 + (lane>>4)*8;
                bf16x8 k8h = ld_frag(kh_ + ko);
                bf16x8 k8l = ld_frag(kl_ + ko);
                sacc[t] = mfma16(qa, k8h, sacc[t]);
                sacc[t] = mfma16(qa, k8l, sacc[t]);
                sacc[t] = mfma16(qb, k8h, sacc[t]);
            }
        }
        // ---- A = relu(S)^2 -> split bf16 -> LDS ----
        #pragma unroll
        for (int t=0;t<2;++t){
            #pragma unroll
            for (int r=0;r<4;++r){
                float s = sacc[t][r];
                s = s > 0.f ? s*s : 0.f;
                u16 hh, ll; split_bf16(s, hh, ll);
                int ar = si*16 + (lane>>4)*4 + r;
                int ac = (sjb+t)*16 + (lane&15);
                A[0][ar][ac] = hh;
                A[1][ar][ac] = ll;
            }
        }
        __syncthreads();
        // ---- V += A @ v ----
        #pragma unroll
        for (int kstep=0;kstep<2;++kstep){
            bf16x8 Ah[4], Al[4];
            #pragma unroll
            for (int rf=0;rf<4;++rf){
                Ah[rf] = ld_frag(&A[0][rf*16 + (lane&15)][((lane>>4) + kstep*4)*8]);
                Al[rf] = ld_frag(&A[1][rf*16 + (lane&15)][((lane>>4) + kstep*4)*8]);
            }
            #pragma unroll
            for (int cf=0;cf<8;++cf){
                int d = wave*128 + cf*16 + (lane&15);
                size_t vo = ((size_t)(batch*HID + d))*SEQ + kt*64 + kstep*32 + (lane>>4)*8;
                bf16x8 Bh = ld_frag(vth + vo);
                bf16x8 Bl = ld_frag(vtl + vo);
                #pragma unroll
                for (int rf=0;rf<4;++rf){
                    acc[rf][cf] = mfma16(Ah[rf], Bh, acc[rf][cf]);
                    acc[rf][cf] = mfma16(Ah[rf], Bl, acc[rf][cf]);
                    acc[rf][cf] = mfma16(Al[rf], Bh, acc[rf][cf]);
                }
            }
        }
        __syncthreads();
    }
    // ---- epilogue: Vg = V * gate * 2^-24 (in place over gate) ----
    #pragma unroll
    for (int rf=0;rf<4;++rf){
        #pragma unroll
        for (int cf=0;cf<8;++cf){
            #pragma unroll
            for (int r=0;r<4;++r){
                int i = i0 + rf*16 + (lane>>4)*4 + r;
                int d = wave*128 + cf*16 + (lane&15);
                size_t go = ((size_t)(batch*SEQ + i))*HID + d;
                float g = gate[go];
                gate[go] = acc[rf][cf][r] * g * 0x1p-24f;
            }
        }
    }
}

// ---------- K5: out = Vg @ Wo + bo ----------
__global__ __launch_bounds__(256) void wo_kernel(const float* __restrict__ vg,
                                                 const float* __restrict__ Wo,
                                                 const float* __restrict__ bo,
                                                 float* out){
    int wave = threadIdx.x>>6, lane = threadIdx.x&63;
    int row  = blockIdx.x*4 + wave;
    const float* vr = vg + (size_t)row*HID;
    float po[8] = {};
    #pragma unroll
    for (int c=0;c<4;++c){
        float4 v = *(const float4*)(vr + c*256 + lane*4);
        float vv[4] = {v.x, v.y, v.z, v.w};
        #pragma unroll
        for (int e=0;e<4;++e){
            int col = c*256 + lane*4 + e;
            float4 w0 = *(const float4*)(Wo + (size_t)col*8);
            float4 w1 = *(const float4*)(Wo + (size_t)col*8 + 4);
            po[0] += vv[e]*w0.x; po[1] += vv[e]*w0.y; po[2] += vv[e]*w0.z; po[3] += vv[e]*w0.w;
            po[4] += vv[e]*w1.x; po[5] += vv[e]*w1.y; po[6] += vv[e]*w1.z; po[7] += vv[e]*w1.w;
        }
    }
    #pragma unroll
    for (int m=1;m<64;m<<=1){
        #pragma unroll
        for (int o=0;o<8;++o) po[o] += __shfl_xor(po[o], m, 64);
    }
    if (lane == 0){
        #pragma unroll
        for (int o=0;o<8;++o) out[(size_t)row*8 + o] = po[o] + bo[o];
    }
}

// ---------- launch ----------
extern "C" void kernel_launch(void* const* d_in, const int* in_sizes, int n_in,
                              void* d_out, int out_size, void* d_ws, size_t ws_size,
                              hipStream_t stream){
    const float* x    = (const float*)d_in[0];
    const float* ln_g = (const float*)d_in[1];
    const float* ln_b = (const float*)d_in[2];
    const float* Wh   = (const float*)d_in[3];
    const float* bh   = (const float*)d_in[4];
    const float* Wqk  = (const float*)d_in[5];
    const float* bqk  = (const float*)d_in[6];
    const float* gamma= (const float*)d_in[7];
    const float* beta = (const float*)d_in[8];
    const float* Wo   = (const float*)d_in[9];
    const float* bo   = (const float*)d_in[10];
    float* out = (float*)d_out;

    char* w = (char*)d_ws;
    auto alloc = [&](size_t bytes)->char*{
        char* p = w; w += (bytes + 255) & ~(size_t)255; return p;
    };
    u16* nh    = (u16*)alloc((size_t)ROWS*DIM*2);
    u16* nl    = (u16*)alloc((size_t)ROWS*DIM*2);
    u16* whth  = (u16*)alloc((size_t)HID2*DIM*2);
    u16* whtl  = (u16*)alloc((size_t)HID2*DIM*2);
    u16* wqkth = (u16*)alloc((size_t)QKD*DIM*2);
    u16* wqktl = (u16*)alloc((size_t)QKD*DIM*2);
    u16* qh    = (u16*)alloc((size_t)ROWS*QKD*2);
    u16* ql    = (u16*)alloc((size_t)ROWS*QKD*2);
    u16* kh    = (u16*)alloc((size_t)ROWS*QKD*2);
    u16* kl    = (u16*)alloc((size_t)ROWS*QKD*2);
    u16* vth   = (u16*)alloc((size_t)BATCH*HID*SEQ*2);
    u16* vtl   = (u16*)alloc((size_t)BATCH*HID*SEQ*2);
    float* gate= (float*)alloc((size_t)ROWS*HID*4);

    prep_split<<<(HID2*DIM + QKD*DIM)/256, 256, 0, stream>>>(Wh, Wqk, whth, whtl, wqkth, wqktl);
    ln_kernel<<<ROWS/4, 256, 0, stream>>>(x, ln_g, ln_b, nh, nl);
    gemm_h<<<dim3(HID2/128, ROWS/128), 256, 0, stream>>>(nh, nl, whth, whtl, bh, vth, vtl, gate);
    gemm_qk<<<ROWS/128, 256, 0, stream>>>(nh, nl, wqkth, wqktl, bqk, gamma, beta, qh, ql, kh, kl);
    attn<<<BATCH*SEQ/64, 512, 0, stream>>>(qh, ql, kh, kl, vth, vtl, gate);
    wo_kernel<<<ROWS/4, 256, 0, stream>>>(gate, Wo, bo, out);
}

// Round 2
// 924.112 us; speedup vs baseline: 1.1377x; 1.1377x over previous
//
#include <hip/hip_runtime.h>
#include <stdint.h>

#define DIM   512
#define QKD   128
#define HID   1024
#define HID2  2048
#define OUTD  8
#define BATCH 4
#define SEQ   4096
#define ROWS  (BATCH*SEQ)   // 16384
#define LN_EPS 1e-5f

typedef unsigned short u16;
typedef __bf16 bf16x8 __attribute__((ext_vector_type(8)));
typedef float  f32x4  __attribute__((ext_vector_type(4)));

// ---------- helpers ----------
__device__ inline u16 f2bf(float f){
    uint32_t u = __builtin_bit_cast(uint32_t, f);
    u += 0x7FFFu + ((u >> 16) & 1u);   // RNE
    return (u16)(u >> 16);
}
__device__ inline float bf2f(u16 h){
    uint32_t u = ((uint32_t)h) << 16;
    return __builtin_bit_cast(float, u);
}
__device__ inline void split_bf16(float x, u16 &hi, u16 &lo){
    hi = f2bf(x);
    float r = x - bf2f(hi);
    lo = f2bf(r);
}
__device__ inline bf16x8 ld_frag(const u16* p){
    uint4 r = *reinterpret_cast<const uint4*>(p);
    return __builtin_bit_cast(bf16x8, r);
}
__device__ inline f32x4 mfma16(bf16x8 a, bf16x8 b, f32x4 c){
    return __builtin_amdgcn_mfma_f32_16x16x32_bf16(a, b, c, 0, 0, 0);
}
__device__ inline float silu(float x){ return x / (1.f + expf(-x)); }

// ---------- P: split + transpose weights ----------
__global__ void prep_split(const float* __restrict__ Wh, const float* __restrict__ Wqk,
                           u16* whth, u16* whtl, u16* wqkth, u16* wqktl){
    int tid = blockIdx.x*256 + threadIdx.x;
    const int NWH = HID2*DIM;            // 1048576
    if (tid < NWH){
        int k = tid & (DIM-1);
        int n = tid >> 9;
        float w = Wh[(size_t)k*HID2 + n];
        u16 h,l; split_bf16(w,h,l);
        whth[tid]=h; whtl[tid]=l;
    } else {
        int t2 = tid - NWH;
        if (t2 < QKD*DIM){
            int k = t2 & (DIM-1);
            int n = t2 >> 9;
            float w = Wqk[(size_t)k*QKD + n];
            u16 h,l; split_bf16(w,h,l);
            wqkth[t2]=h; wqktl[t2]=l;
        }
    }
}

// ---------- K1: layernorm -> split bf16 ----------
__global__ __launch_bounds__(256) void ln_kernel(const float* __restrict__ x,
                                                 const float* __restrict__ g,
                                                 const float* __restrict__ b,
                                                 u16* nh, u16* nl){
    int wave = threadIdx.x >> 6, lane = threadIdx.x & 63;
    int row  = blockIdx.x*4 + wave;
    const float* xr = x + (size_t)row*DIM;
    float4 v0 = *(const float4*)(xr + lane*8);
    float4 v1 = *(const float4*)(xr + lane*8 + 4);
    float xs[8] = {v0.x,v0.y,v0.z,v0.w,v1.x,v1.y,v1.z,v1.w};
    float s = 0.f, q = 0.f;
    #pragma unroll
    for (int i=0;i<8;++i){ s += xs[i]; q += xs[i]*xs[i]; }
    #pragma unroll
    for (int m=1;m<64;m<<=1){ s += __shfl_xor(s,m,64); q += __shfl_xor(q,m,64); }
    float mean = s * (1.f/DIM);
    float var  = q * (1.f/DIM) - mean*mean;
    float rstd = rsqrtf(var + LN_EPS);
    float4 g0 = *(const float4*)(g + lane*8);
    float4 g1 = *(const float4*)(g + lane*8 + 4);
    float4 b0 = *(const float4*)(b + lane*8);
    float4 b1 = *(const float4*)(b + lane*8 + 4);
    float gs[8] = {g0.x,g0.y,g0.z,g0.w,g1.x,g1.y,g1.z,g1.w};
    float bs[8] = {b0.x,b0.y,b0.z,b0.w,b1.x,b1.y,b1.z,b1.w};
    u16 hh[8], ll[8];
    #pragma unroll
    for (int i=0;i<8;++i){
        float nv = (xs[i]-mean)*rstd*gs[i] + bs[i];
        split_bf16(nv, hh[i], ll[i]);
    }
    size_t o = (size_t)row*DIM + lane*8;
    *(uint4*)(nh + o) = *(uint4*)hh;
    *(uint4*)(nl + o) = *(uint4*)ll;
}

// ---------- K2: hidden = silu(n @ Wh + bh) -> v^T (hi only) + gate ----------
__global__ __launch_bounds__(256,2) void gemm_h(
        const u16* __restrict__ nh, const u16* __restrict__ nl,
        const u16* __restrict__ bth, const u16* __restrict__ btl,
        const float* __restrict__ bh,
        u16* vth, float* gate){
    __shared__ __align__(16) u16 At[2][128][40];
    __shared__ __align__(16) u16 Bt[2][128][40];
    int n0 = blockIdx.x * 128;
    int m0 = blockIdx.y * 128;
    int wave = threadIdx.x>>6, lane = threadIdx.x&63;
    int wr = wave>>1, wc = wave&1;
    f32x4 acc[4][4] = {};
    for (int ks=0; ks<16; ++ks){
        #pragma unroll
        for (int r=0;r<2;++r){
            int idx = r*256 + threadIdx.x;   // 0..511
            int row = idx>>2, ch = idx&3;
            size_t ga = (size_t)(m0+row)*DIM + ks*32 + ch*8;
            size_t gb = (size_t)(n0+row)*DIM + ks*32 + ch*8;
            *(uint4*)&At[0][row][ch*8] = *(const uint4*)(nh + ga);
            *(uint4*)&At[1][row][ch*8] = *(const uint4*)(nl + ga);
            *(uint4*)&Bt[0][row][ch*8] = *(const uint4*)(bth + gb);
            *(uint4*)&Bt[1][row][ch*8] = *(const uint4*)(btl + gb);
        }
        __syncthreads();
        bf16x8 Ah[4], Al[4];
        #pragma unroll
        for (int rf=0;rf<4;++rf){
            Ah[rf] = ld_frag(&At[0][wr*64 + rf*16 + (lane&15)][(lane>>4)*8]);
            Al[rf] = ld_frag(&At[1][wr*64 + rf*16 + (lane&15)][(lane>>4)*8]);
        }
        #pragma unroll
        for (int cf=0;cf<4;++cf){
            bf16x8 Bh = ld_frag(&Bt[0][wc*64 + cf*16 + (lane&15)][(lane>>4)*8]);
            bf16x8 Bl = ld_frag(&Bt[1][wc*64 + cf*16 + (lane&15)][(lane>>4)*8]);
            #pragma unroll
            for (int rf=0;rf<4;++rf){
                acc[rf][cf] = mfma16(Ah[rf], Bh, acc[rf][cf]);
                acc[rf][cf] = mfma16(Ah[rf], Bl, acc[rf][cf]);
                acc[rf][cf] = mfma16(Al[rf], Bh, acc[rf][cf]);
            }
        }
        __syncthreads();
    }
    #pragma unroll
    for (int rf=0;rf<4;++rf){
        #pragma unroll
        for (int cf=0;cf<4;++cf){
            #pragma unroll
            for (int r=0;r<4;++r){
                int row = m0 + wr*64 + rf*16 + (lane>>4)*4 + r;
                int col = n0 + wc*64 + cf*16 + (lane&15);
                float h = acc[rf][cf][r] + bh[col];
                float s = silu(h);
                if (col < HID){
                    int b = row >> 12, i = row & (SEQ-1);
                    size_t o = ((size_t)b*HID + col)*SEQ + i;
                    vth[o] = f2bf(s);
                } else {
                    gate[(size_t)row*HID + (col - HID)] = s;
                }
            }
        }
    }
}

// ---------- K3: Z = silu(n @ Wqk + bqk); q,k = Z*gamma+beta -> split ----------
__global__ __launch_bounds__(256,2) void gemm_qk(
        const u16* __restrict__ nh, const u16* __restrict__ nl,
        const u16* __restrict__ bth, const u16* __restrict__ btl,
        const float* __restrict__ bqk, const float* __restrict__ gamma,
        const float* __restrict__ beta,
        u16* qh, u16* ql, u16* kh, u16* kl){
    __shared__ __align__(16) u16 At[2][128][40];
    __shared__ __align__(16) u16 Bt[2][128][40];
    int m0 = blockIdx.x * 128;
    int wave = threadIdx.x>>6, lane = threadIdx.x&63;
    int wr = wave>>1, wc = wave&1;
    f32x4 acc[4][4] = {};
    for (int ks=0; ks<16; ++ks){
        #pragma unroll
        for (int r=0;r<2;++r){
            int idx = r*256 + threadIdx.x;
            int row = idx>>2, ch = idx&3;
            size_t ga = (size_t)(m0+row)*DIM + ks*32 + ch*8;
            size_t gb = (size_t)row*DIM + ks*32 + ch*8;   // n0 = 0, N=128
            *(uint4*)&At[0][row][ch*8] = *(const uint4*)(nh + ga);
            *(uint4*)&At[1][row][ch*8] = *(const uint4*)(nl + ga);
            *(uint4*)&Bt[0][row][ch*8] = *(const uint4*)(bth + gb);
            *(uint4*)&Bt[1][row][ch*8] = *(const uint4*)(btl + gb);
        }
        __syncthreads();
        bf16x8 Ah[4], Al[4];
        #pragma unroll
        for (int rf=0;rf<4;++rf){
            Ah[rf] = ld_frag(&At[0][wr*64 + rf*16 + (lane&15)][(lane>>4)*8]);
            Al[rf] = ld_frag(&At[1][wr*64 + rf*16 + (lane&15)][(lane>>4)*8]);
        }
        #pragma unroll
        for (int cf=0;cf<4;++cf){
            bf16x8 Bh = ld_frag(&Bt[0][wc*64 + cf*16 + (lane&15)][(lane>>4)*8]);
            bf16x8 Bl = ld_frag(&Bt[1][wc*64 + cf*16 + (lane&15)][(lane>>4)*8]);
            #pragma unroll
            for (int rf=0;rf<4;++rf){
                acc[rf][cf] = mfma16(Ah[rf], Bh, acc[rf][cf]);
                acc[rf][cf] = mfma16(Ah[rf], Bl, acc[rf][cf]);
                acc[rf][cf] = mfma16(Al[rf], Bh, acc[rf][cf]);
            }
        }
        __syncthreads();
    }
    #pragma unroll
    for (int rf=0;rf<4;++rf){
        #pragma unroll
        for (int cf=0;cf<4;++cf){
            #pragma unroll
            for (int r=0;r<4;++r){
                int row = m0 + wr*64 + rf*16 + (lane>>4)*4 + r;
                int col = wc*64 + cf*16 + (lane&15);
                float z = silu(acc[rf][cf][r] + bqk[col]);
                float qv = z*gamma[col]       + beta[col];
                float kv = z*gamma[QKD + col] + beta[QKD + col];
                size_t o = (size_t)row*QKD + col;
                u16 h_, l_;
                split_bf16(qv, h_, l_); qh[o]=h_; ql[o]=l_;
                split_bf16(kv, h_, l_); kh[o]=h_; kl[o]=l_;
            }
        }
    }
}

// ---------- K4: fused squared-relu attention ----------
// grid = 512 blocks (2/CU), 512 threads (8 waves). Block: batch + 32-row q tile.
// Each wave owns a 128-wide d slice. gate is overwritten with V*gate/n^2.
__global__ __launch_bounds__(512,4) void attn(
        const u16* __restrict__ qh_, const u16* __restrict__ ql_,
        const u16* __restrict__ kh_, const u16* __restrict__ kl_,
        const u16* __restrict__ vth,
        float* gate){
    __shared__ __align__(16) u16 Q[2][32][136];
    __shared__ __align__(16) u16 A[2][2][32][72];   // [buf][hi/lo][row][col]
    int bid   = blockIdx.x;
    int xcd   = bid & 7;
    int batch = xcd >> 1;                      // 2 XCDs per batch (L2 locality)
    int qt    = ((bid >> 3) << 1) | (xcd & 1); // 0..127
    int i0    = qt * 32;
    int w     = threadIdx.x >> 6, lane = threadIdx.x & 63;

    // stage q tile (hi/lo) into LDS
    {
        int row = threadIdx.x >> 4, ch = threadIdx.x & 15;
        size_t o = ((size_t)(batch*SEQ + i0 + row))*QKD + ch*8;
        *(uint4*)&Q[0][row][ch*8] = *(const uint4*)(qh_ + o);
        *(uint4*)&Q[1][row][ch*8] = *(const uint4*)(ql_ + o);
    }
    __syncthreads();

    f32x4 acc[2][8] = {};
    int sr = w >> 2, sc = w & 3;

    for (int kt=0; kt<64; ++kt){
        // ---- S = q.k^T (raw, unscaled), wave computes 16x16 frag ----
        f32x4 sacc = {};
        #pragma unroll
        for (int kstep=0;kstep<4;++kstep){
            bf16x8 qa = ld_frag(&Q[0][sr*16 + (lane&15)][((lane>>4) + kstep*4)*8]);
            bf16x8 qb = ld_frag(&Q[1][sr*16 + (lane&15)][((lane>>4) + kstep*4)*8]);
            int j = batch*SEQ + kt*64 + sc*16 + (lane&15);
            size_t ko = (size_t)j*QKD + kstep*32 + (lane>>4)*8;
            bf16x8 k8h = ld_frag(kh_ + ko);
            bf16x8 k8l = ld_frag(kl_ + ko);
            sacc = mfma16(qa, k8h, sacc);
            sacc = mfma16(qa, k8l, sacc);
            sacc = mfma16(qb, k8h, sacc);
        }
        // ---- A = relu(S)^2 -> split bf16 -> LDS (double-buffered) ----
        int p = kt & 1;
        #pragma unroll
        for (int r=0;r<4;++r){
            float s = sacc[r];
            s = s > 0.f ? s*s : 0.f;
            u16 hh, ll; split_bf16(s, hh, ll);
            int ar = sr*16 + (lane>>4)*4 + r;
            int ac = sc*16 + (lane&15);
            A[p][0][ar][ac] = hh;
            A[p][1][ar][ac] = ll;
        }
        __syncthreads();
        // ---- V += A @ v (A split hi+lo, v hi-only) ----
        #pragma unroll
        for (int kstep=0;kstep<2;++kstep){
            bf16x8 Ah[2], Al[2];
            #pragma unroll
            for (int rf=0;rf<2;++rf){
                Ah[rf] = ld_frag(&A[p][0][rf*16 + (lane&15)][kstep*32 + (lane>>4)*8]);
                Al[rf] = ld_frag(&A[p][1][rf*16 + (lane&15)][kstep*32 + (lane>>4)*8]);
            }
            #pragma unroll
            for (int cf=0;cf<8;++cf){
                int d = w*128 + cf*16 + (lane&15);
                size_t vo = ((size_t)(batch*HID + d))*SEQ + kt*64 + kstep*32 + (lane>>4)*8;
                bf16x8 Bh = ld_frag(vth + vo);
                #pragma unroll
                for (int rf=0;rf<2;++rf){
                    acc[rf][cf] = mfma16(Ah[rf], Bh, acc[rf][cf]);
                    acc[rf][cf] = mfma16(Al[rf], Bh, acc[rf][cf]);
                }
            }
        }
    }
    // ---- epilogue: Vg = V * gate * 2^-24 (in place over gate) ----
    #pragma unroll
    for (int rf=0;rf<2;++rf){
        #pragma unroll
        for (int cf=0;cf<8;++cf){
            #pragma unroll
            for (int r=0;r<4;++r){
                int i = i0 + rf*16 + (lane>>4)*4 + r;
                int d = w*128 + cf*16 + (lane&15);
                size_t go = ((size_t)(batch*SEQ + i))*HID + d;
                float g = gate[go];
                gate[go] = acc[rf][cf][r] * g * 0x1p-24f;
            }
        }
    }
}

// ---------- K5: out = Vg @ Wo + bo ----------
__global__ __launch_bounds__(256) void wo_kernel(const float* __restrict__ vg,
                                                 const float* __restrict__ Wo,
                                                 const float* __restrict__ bo,
                                                 float* out){
    int wave = threadIdx.x>>6, lane = threadIdx.x&63;
    int row  = blockIdx.x*4 + wave;
    const float* vr = vg + (size_t)row*HID;
    float po[8] = {};
    #pragma unroll
    for (int c=0;c<4;++c){
        float4 v = *(const float4*)(vr + c*256 + lane*4);
        float vv[4] = {v.x, v.y, v.z, v.w};
        #pragma unroll
        for (int e=0;e<4;++e){
            int col = c*256 + lane*4 + e;
            float4 w0 = *(const float4*)(Wo + (size_t)col*8);
            float4 w1 = *(const float4*)(Wo + (size_t)col*8 + 4);
            po[0] += vv[e]*w0.x; po[1] += vv[e]*w0.y; po[2] += vv[e]*w0.z; po[3] += vv[e]*w0.w;
            po[4] += vv[e]*w1.x; po[5] += vv[e]*w1.y; po[6] += vv[e]*w1.z; po[7] += vv[e]*w1.w;
        }
    }
    #pragma unroll
    for (int m=1;m<64;m<<=1){
        #pragma unroll
        for (int o=0;o<8;++o) po[o] += __shfl_xor(po[o], m, 64);
    }
    if (lane == 0){
        #pragma unroll
        for (int o=0;o<8;++o) out[(size_t)row*8 + o] = po[o] + bo[o];
    }
}

// ---------- launch ----------
extern "C" void kernel_launch(void* const* d_in, const int* in_sizes, int n_in,
                              void* d_out, int out_size, void* d_ws, size_t ws_size,
                              hipStream_t stream){
    const float* x    = (const float*)d_in[0];
    const float* ln_g = (const float*)d_in[1];
    const float* ln_b = (const float*)d_in[2];
    const float* Wh   = (const float*)d_in[3];
    const float* bh   = (const float*)d_in[4];
    const float* Wqk  = (const float*)d_in[5];
    const float* bqk  = (const float*)d_in[6];
    const float* gamma= (const float*)d_in[7];
    const float* beta = (const float*)d_in[8];
    const float* Wo   = (const float*)d_in[9];
    const float* bo   = (const float*)d_in[10];
    float* out = (float*)d_out;

    char* w = (char*)d_ws;
    auto alloc = [&](size_t bytes)->char*{
        char* p = w; w += (bytes + 255) & ~(size_t)255; return p;
    };
    u16* nh    = (u16*)alloc((size_t)ROWS*DIM*2);
    u16* nl    = (u16*)alloc((size_t)ROWS*DIM*2);
    u16* whth  = (u16*)alloc((size_t)HID2*DIM*2);
    u16* whtl  = (u16*)alloc((size_t)HID2*DIM*2);
    u16* wqkth = (u16*)alloc((size_t)QKD*DIM*2);
    u16* wqktl = (u16*)alloc((size_t)QKD*DIM*2);
    u16* qh    = (u16*)alloc((size_t)ROWS*QKD*2);
    u16* ql    = (u16*)alloc((size_t)ROWS*QKD*2);
    u16* kh    = (u16*)alloc((size_t)ROWS*QKD*2);
    u16* kl    = (u16*)alloc((size_t)ROWS*QKD*2);
    u16* vth   = (u16*)alloc((size_t)BATCH*HID*SEQ*2);
    float* gate= (float*)alloc((size_t)ROWS*HID*4);

    prep_split<<<(HID2*DIM + QKD*DIM)/256, 256, 0, stream>>>(Wh, Wqk, whth, whtl, wqkth, wqktl);
    ln_kernel<<<ROWS/4, 256, 0, stream>>>(x, ln_g, ln_b, nh, nl);
    gemm_h<<<dim3(HID2/128, ROWS/128), 256, 0, stream>>>(nh, nl, whth, whtl, bh, vth, gate);
    gemm_qk<<<ROWS/128, 256, 0, stream>>>(nh, nl, wqkth, wqktl, bqk, gamma, beta, qh, ql, kh, kl);
    attn<<<512, 512, 0, stream>>>(qh, ql, kh, kl, vth, gate);
    wo_kernel<<<ROWS/4, 256, 0, stream>>>(gate, Wo, bo, out);
}

// Round 3
// 635.764 us; speedup vs baseline: 1.6537x; 1.4535x over previous
//
#include <hip/hip_runtime.h>
#include <stdint.h>

#define DIM   512
#define QKD   128
#define HID   1024
#define HID2  2048
#define OUTD  8
#define BATCH 4
#define SEQ   4096
#define ROWS  (BATCH*SEQ)   // 16384
#define LN_EPS 1e-5f

typedef unsigned short u16;
typedef __bf16 bf16x8 __attribute__((ext_vector_type(8)));
typedef float  f32x4  __attribute__((ext_vector_type(4)));

// ---------- helpers ----------
__device__ inline u16 f2bf(float f){
    uint32_t u = __builtin_bit_cast(uint32_t, f);
    u += 0x7FFFu + ((u >> 16) & 1u);   // RNE
    return (u16)(u >> 16);
}
__device__ inline float bf2f(u16 h){
    uint32_t u = ((uint32_t)h) << 16;
    return __builtin_bit_cast(float, u);
}
__device__ inline void split_bf16(float x, u16 &hi, u16 &lo){
    hi = f2bf(x);
    float r = x - bf2f(hi);
    lo = f2bf(r);
}
__device__ inline bf16x8 ld_frag(const u16* p){
    uint4 r = *reinterpret_cast<const uint4*>(p);
    return __builtin_bit_cast(bf16x8, r);
}
__device__ inline f32x4 mfma16(bf16x8 a, bf16x8 b, f32x4 c){
    return __builtin_amdgcn_mfma_f32_16x16x32_bf16(a, b, c, 0, 0, 0);
}
__device__ inline float silu(float x){ return x / (1.f + expf(-x)); }

// ---------- P: split + transpose weights ----------
__global__ void prep_split(const float* __restrict__ Wh, const float* __restrict__ Wqk,
                           u16* whth, u16* whtl, u16* wqkth, u16* wqktl){
    int tid = blockIdx.x*256 + threadIdx.x;
    const int NWH = HID2*DIM;            // 1048576
    if (tid < NWH){
        int k = tid & (DIM-1);
        int n = tid >> 9;
        float w = Wh[(size_t)k*HID2 + n];
        u16 h,l; split_bf16(w,h,l);
        whth[tid]=h; whtl[tid]=l;
    } else {
        int t2 = tid - NWH;
        if (t2 < QKD*DIM){
            int k = t2 & (DIM-1);
            int n = t2 >> 9;
            float w = Wqk[(size_t)k*QKD + n];
            u16 h,l; split_bf16(w,h,l);
            wqkth[t2]=h; wqktl[t2]=l;
        }
    }
}

// ---------- K1: layernorm -> split bf16 ----------
__global__ __launch_bounds__(256) void ln_kernel(const float* __restrict__ x,
                                                 const float* __restrict__ g,
                                                 const float* __restrict__ b,
                                                 u16* nh, u16* nl){
    int wave = threadIdx.x >> 6, lane = threadIdx.x & 63;
    int row  = blockIdx.x*4 + wave;
    const float* xr = x + (size_t)row*DIM;
    float4 v0 = *(const float4*)(xr + lane*8);
    float4 v1 = *(const float4*)(xr + lane*8 + 4);
    float xs[8] = {v0.x,v0.y,v0.z,v0.w,v1.x,v1.y,v1.z,v1.w};
    float s = 0.f, q = 0.f;
    #pragma unroll
    for (int i=0;i<8;++i){ s += xs[i]; q += xs[i]*xs[i]; }
    #pragma unroll
    for (int m=1;m<64;m<<=1){ s += __shfl_xor(s,m,64); q += __shfl_xor(q,m,64); }
    float mean = s * (1.f/DIM);
    float var  = q * (1.f/DIM) - mean*mean;
    float rstd = rsqrtf(var + LN_EPS);
    float4 g0 = *(const float4*)(g + lane*8);
    float4 g1 = *(const float4*)(g + lane*8 + 4);
    float4 b0 = *(const float4*)(b + lane*8);
    float4 b1 = *(const float4*)(b + lane*8 + 4);
    float gs[8] = {g0.x,g0.y,g0.z,g0.w,g1.x,g1.y,g1.z,g1.w};
    float bs[8] = {b0.x,b0.y,b0.z,b0.w,b1.x,b1.y,b1.z,b1.w};
    u16 hh[8], ll[8];
    #pragma unroll
    for (int i=0;i<8;++i){
        float nv = (xs[i]-mean)*rstd*gs[i] + bs[i];
        split_bf16(nv, hh[i], ll[i]);
    }
    size_t o = (size_t)row*DIM + lane*8;
    *(uint4*)(nh + o) = *(uint4*)hh;
    *(uint4*)(nl + o) = *(uint4*)ll;
}

// ---------- K2: hidden = silu(n @ Wh + bh) -> v^T (hi only) + gate ----------
__global__ __launch_bounds__(256,2) void gemm_h(
        const u16* __restrict__ nh, const u16* __restrict__ nl,
        const u16* __restrict__ bth, const u16* __restrict__ btl,
        const float* __restrict__ bh,
        u16* vth, float* gate){
    __shared__ __align__(16) u16 At[2][128][40];
    __shared__ __align__(16) u16 Bt[2][128][40];
    int n0 = blockIdx.x * 128;
    int m0 = blockIdx.y * 128;
    int wave = threadIdx.x>>6, lane = threadIdx.x&63;
    int wr = wave>>1, wc = wave&1;
    f32x4 acc[4][4] = {};
    for (int ks=0; ks<16; ++ks){
        #pragma unroll
        for (int r=0;r<2;++r){
            int idx = r*256 + threadIdx.x;   // 0..511
            int row = idx>>2, ch = idx&3;
            size_t ga = (size_t)(m0+row)*DIM + ks*32 + ch*8;
            size_t gb = (size_t)(n0+row)*DIM + ks*32 + ch*8;
            *(uint4*)&At[0][row][ch*8] = *(const uint4*)(nh + ga);
            *(uint4*)&At[1][row][ch*8] = *(const uint4*)(nl + ga);
            *(uint4*)&Bt[0][row][ch*8] = *(const uint4*)(bth + gb);
            *(uint4*)&Bt[1][row][ch*8] = *(const uint4*)(btl + gb);
        }
        __syncthreads();
        bf16x8 Ah[4], Al[4];
        #pragma unroll
        for (int rf=0;rf<4;++rf){
            Ah[rf] = ld_frag(&At[0][wr*64 + rf*16 + (lane&15)][(lane>>4)*8]);
            Al[rf] = ld_frag(&At[1][wr*64 + rf*16 + (lane&15)][(lane>>4)*8]);
        }
        #pragma unroll
        for (int cf=0;cf<4;++cf){
            bf16x8 Bh = ld_frag(&Bt[0][wc*64 + cf*16 + (lane&15)][(lane>>4)*8]);
            bf16x8 Bl = ld_frag(&Bt[1][wc*64 + cf*16 + (lane&15)][(lane>>4)*8]);
            #pragma unroll
            for (int rf=0;rf<4;++rf){
                acc[rf][cf] = mfma16(Ah[rf], Bh, acc[rf][cf]);
                acc[rf][cf] = mfma16(Ah[rf], Bl, acc[rf][cf]);
                acc[rf][cf] = mfma16(Al[rf], Bh, acc[rf][cf]);
            }
        }
        __syncthreads();
    }
    #pragma unroll
    for (int rf=0;rf<4;++rf){
        #pragma unroll
        for (int cf=0;cf<4;++cf){
            #pragma unroll
            for (int r=0;r<4;++r){
                int row = m0 + wr*64 + rf*16 + (lane>>4)*4 + r;
                int col = n0 + wc*64 + cf*16 + (lane&15);
                float h = acc[rf][cf][r] + bh[col];
                float s = silu(h);
                if (col < HID){
                    int b = row >> 12, i = row & (SEQ-1);
                    size_t o = ((size_t)b*HID + col)*SEQ + i;
                    vth[o] = f2bf(s);
                } else {
                    gate[(size_t)row*HID + (col - HID)] = s;
                }
            }
        }
    }
}

// ---------- K3: Z = silu(n @ Wqk + bqk); q,k = Z*gamma+beta -> split ----------
__global__ __launch_bounds__(256,2) void gemm_qk(
        const u16* __restrict__ nh, const u16* __restrict__ nl,
        const u16* __restrict__ bth, const u16* __restrict__ btl,
        const float* __restrict__ bqk, const float* __restrict__ gamma,
        const float* __restrict__ beta,
        u16* qh, u16* ql, u16* kh, u16* kl){
    __shared__ __align__(16) u16 At[2][128][40];
    __shared__ __align__(16) u16 Bt[2][128][40];
    int m0 = blockIdx.x * 128;
    int wave = threadIdx.x>>6, lane = threadIdx.x&63;
    int wr = wave>>1, wc = wave&1;
    f32x4 acc[4][4] = {};
    for (int ks=0; ks<16; ++ks){
        #pragma unroll
        for (int r=0;r<2;++r){
            int idx = r*256 + threadIdx.x;
            int row = idx>>2, ch = idx&3;
            size_t ga = (size_t)(m0+row)*DIM + ks*32 + ch*8;
            size_t gb = (size_t)row*DIM + ks*32 + ch*8;   // n0 = 0, N=128
            *(uint4*)&At[0][row][ch*8] = *(const uint4*)(nh + ga);
            *(uint4*)&At[1][row][ch*8] = *(const uint4*)(nl + ga);
            *(uint4*)&Bt[0][row][ch*8] = *(const uint4*)(bth + gb);
            *(uint4*)&Bt[1][row][ch*8] = *(const uint4*)(btl + gb);
        }
        __syncthreads();
        bf16x8 Ah[4], Al[4];
        #pragma unroll
        for (int rf=0;rf<4;++rf){
            Ah[rf] = ld_frag(&At[0][wr*64 + rf*16 + (lane&15)][(lane>>4)*8]);
            Al[rf] = ld_frag(&At[1][wr*64 + rf*16 + (lane&15)][(lane>>4)*8]);
        }
        #pragma unroll
        for (int cf=0;cf<4;++cf){
            bf16x8 Bh = ld_frag(&Bt[0][wc*64 + cf*16 + (lane&15)][(lane>>4)*8]);
            bf16x8 Bl = ld_frag(&Bt[1][wc*64 + cf*16 + (lane&15)][(lane>>4)*8]);
            #pragma unroll
            for (int rf=0;rf<4;++rf){
                acc[rf][cf] = mfma16(Ah[rf], Bh, acc[rf][cf]);
                acc[rf][cf] = mfma16(Ah[rf], Bl, acc[rf][cf]);
                acc[rf][cf] = mfma16(Al[rf], Bh, acc[rf][cf]);
            }
        }
        __syncthreads();
    }
    #pragma unroll
    for (int rf=0;rf<4;++rf){
        #pragma unroll
        for (int cf=0;cf<4;++cf){
            #pragma unroll
            for (int r=0;r<4;++r){
                int row = m0 + wr*64 + rf*16 + (lane>>4)*4 + r;
                int col = wc*64 + cf*16 + (lane&15);
                float z = silu(acc[rf][cf][r] + bqk[col]);
                float qv = z*gamma[col]       + beta[col];
                float kv = z*gamma[QKD + col] + beta[QKD + col];
                size_t o = (size_t)row*QKD + col;
                u16 h_, l_;
                split_bf16(qv, h_, l_); qh[o]=h_; ql[o]=l_;
                split_bf16(kv, h_, l_); kh[o]=h_; kl[o]=l_;
            }
        }
    }
}

// ---------- K4: fused squared-relu attention, LDS-staged flash structure ----------
// grid = 512 blocks (2/CU), 512 threads (8 waves).
// Block: (batch, d-half 512, 64-row q tile). KV tile = 32 rows.
// Waves: each computes one 16x16 S frag (8 frags = 64x32 S tile),
// then PV on its own 64-wide d slice. gate overwritten with V*gate/n^2.
__global__ __launch_bounds__(512,4) void attn(
        const u16* __restrict__ qh_, const u16* __restrict__ ql_,
        const u16* __restrict__ kh_, const u16* __restrict__ kl_,
        const u16* __restrict__ vth,
        float* gate){
    __shared__ __align__(16) u16 Kt[2][32][136];   // [hi/lo][j][d], pad 136 (2-way max)
    __shared__ __align__(16) u16 Vt[512][40];      // [d][j], pad 40 (2-way max)
    __shared__ __align__(16) u16 At[64][40];       // [i][j] bf16 of relu(S)^2
    int bid   = blockIdx.x;
    int xcd   = bid & 7;
    int batch = xcd >> 1;        // 2 XCDs per batch
    int dhalf = xcd & 1;         // XCD pair splits d -> 4MB v-half ~ L2-resident
    int qt    = bid >> 3;        // 0..63
    int i0    = qt * 64;
    int d0    = dhalf * 512;
    int w     = threadIdx.x >> 6, lane = threadIdx.x & 63;
    int fr    = w >> 1, fc = w & 1;   // S frag coords: rows fr*16, cols fc*16

    // ---- Q fragments (loop-invariant): direct from global, once ----
    bf16x8 qfh[4], qfl[4];
    {
        size_t base = ((size_t)(batch*SEQ + i0 + fr*16 + (lane&15)))*QKD + (lane>>4)*8;
        #pragma unroll
        for (int ks=0; ks<4; ++ks){
            qfh[ks] = ld_frag(qh_ + base + ks*32);
            qfl[ks] = ld_frag(ql_ + base + ks*32);
        }
    }

    f32x4 acc[4][4] = {};   // 64 q-rows x 64 d-cols per wave

    for (int kt=0; kt<128; ++kt){
        // ---- stage K(hi/lo) + V tiles, coalesced ----
        {
            int row = threadIdx.x >> 4, c = threadIdx.x & 15;   // K: 32 rows x 256B
            size_t kg = ((size_t)(batch*SEQ + kt*32 + row))*QKD + c*8;
            uint4 ka = *(const uint4*)(kh_ + kg);
            uint4 kb = *(const uint4*)(kl_ + kg);
            *(uint4*)&Kt[0][row][c*8] = ka;
            *(uint4*)&Kt[1][row][c*8] = kb;
            int dr = threadIdx.x >> 2, qq = threadIdx.x & 3;    // V: 128 d-rows x 64B per issue
            #pragma unroll
            for (int s=0; s<4; ++s){
                size_t vg = ((size_t)(batch*HID + d0 + s*128 + dr))*SEQ + kt*32 + qq*8;
                uint4 vv = *(const uint4*)(vth + vg);
                *(uint4*)&Vt[s*128 + dr][qq*8] = vv;
            }
        }
        __syncthreads();
        // ---- S = q.k^T (one 16x16 frag per wave), A = bf16(relu(S)^2) -> LDS ----
        {
            f32x4 sacc = {};
            #pragma unroll
            for (int ks=0; ks<4; ++ks){
                bf16x8 kfh = ld_frag(&Kt[0][fc*16 + (lane&15)][ks*32 + (lane>>4)*8]);
                bf16x8 kfl = ld_frag(&Kt[1][fc*16 + (lane&15)][ks*32 + (lane>>4)*8]);
                sacc = mfma16(qfh[ks], kfh, sacc);
                sacc = mfma16(qfh[ks], kfl, sacc);
                sacc = mfma16(qfl[ks], kfh, sacc);
            }
            #pragma unroll
            for (int r=0; r<4; ++r){
                float s = sacc[r];
                s = s > 0.f ? s*s : 0.f;
                At[fr*16 + (lane>>4)*4 + r][fc*16 + (lane&15)] = f2bf(s);
            }
        }
        __syncthreads();
        // ---- PV: acc[qr][dc] += A @ v on wave's 64-d slice ----
        {
            bf16x8 af[4];
            #pragma unroll
            for (int qr=0; qr<4; ++qr)
                af[qr] = ld_frag(&At[qr*16 + (lane&15)][(lane>>4)*8]);
            #pragma unroll
            for (int dc=0; dc<4; ++dc){
                bf16x8 vb = ld_frag(&Vt[w*64 + dc*16 + (lane&15)][(lane>>4)*8]);
                #pragma unroll
                for (int qr=0; qr<4; ++qr)
                    acc[qr][dc] = mfma16(af[qr], vb, acc[qr][dc]);
            }
        }
        __syncthreads();   // protect K/V/A before next stage
    }
    // ---- epilogue: gate <- V * gate * 2^-24 ----
    #pragma unroll
    for (int qr=0; qr<4; ++qr){
        #pragma unroll
        for (int dc=0; dc<4; ++dc){
            #pragma unroll
            for (int r=0; r<4; ++r){
                int i = i0 + qr*16 + (lane>>4)*4 + r;
                int d = d0 + w*64 + dc*16 + (lane&15);
                size_t go = ((size_t)(batch*SEQ + i))*HID + d;
                float g = gate[go];
                gate[go] = acc[qr][dc][r] * g * 0x1p-24f;
            }
        }
    }
}

// ---------- K5: out = Vg @ Wo + bo ----------
__global__ __launch_bounds__(256) void wo_kernel(const float* __restrict__ vg,
                                                 const float* __restrict__ Wo,
                                                 const float* __restrict__ bo,
                                                 float* out){
    int wave = threadIdx.x>>6, lane = threadIdx.x&63;
    int row  = blockIdx.x*4 + wave;
    const float* vr = vg + (size_t)row*HID;
    float po[8] = {};
    #pragma unroll
    for (int c=0;c<4;++c){
        float4 v = *(const float4*)(vr + c*256 + lane*4);
        float vv[4] = {v.x, v.y, v.z, v.w};
        #pragma unroll
        for (int e=0;e<4;++e){
            int col = c*256 + lane*4 + e;
            float4 w0 = *(const float4*)(Wo + (size_t)col*8);
            float4 w1 = *(const float4*)(Wo + (size_t)col*8 + 4);
            po[0] += vv[e]*w0.x; po[1] += vv[e]*w0.y; po[2] += vv[e]*w0.z; po[3] += vv[e]*w0.w;
            po[4] += vv[e]*w1.x; po[5] += vv[e]*w1.y; po[6] += vv[e]*w1.z; po[7] += vv[e]*w1.w;
        }
    }
    #pragma unroll
    for (int m=1;m<64;m<<=1){
        #pragma unroll
        for (int o=0;o<8;++o) po[o] += __shfl_xor(po[o], m, 64);
    }
    if (lane == 0){
        #pragma unroll
        for (int o=0;o<8;++o) out[(size_t)row*8 + o] = po[o] + bo[o];
    }
}

// ---------- launch ----------
extern "C" void kernel_launch(void* const* d_in, const int* in_sizes, int n_in,
                              void* d_out, int out_size, void* d_ws, size_t ws_size,
                              hipStream_t stream){
    const float* x    = (const float*)d_in[0];
    const float* ln_g = (const float*)d_in[1];
    const float* ln_b = (const float*)d_in[2];
    const float* Wh   = (const float*)d_in[3];
    const float* bh   = (const float*)d_in[4];
    const float* Wqk  = (const float*)d_in[5];
    const float* bqk  = (const float*)d_in[6];
    const float* gamma= (const float*)d_in[7];
    const float* beta = (const float*)d_in[8];
    const float* Wo   = (const float*)d_in[9];
    const float* bo   = (const float*)d_in[10];
    float* out = (float*)d_out;

    char* w = (char*)d_ws;
    auto alloc = [&](size_t bytes)->char*{
        char* p = w; w += (bytes + 255) & ~(size_t)255; return p;
    };
    u16* nh    = (u16*)alloc((size_t)ROWS*DIM*2);
    u16* nl    = (u16*)alloc((size_t)ROWS*DIM*2);
    u16* whth  = (u16*)alloc((size_t)HID2*DIM*2);
    u16* whtl  = (u16*)alloc((size_t)HID2*DIM*2);
    u16* wqkth = (u16*)alloc((size_t)QKD*DIM*2);
    u16* wqktl = (u16*)alloc((size_t)QKD*DIM*2);
    u16* qh    = (u16*)alloc((size_t)ROWS*QKD*2);
    u16* ql    = (u16*)alloc((size_t)ROWS*QKD*2);
    u16* kh    = (u16*)alloc((size_t)ROWS*QKD*2);
    u16* kl    = (u16*)alloc((size_t)ROWS*QKD*2);
    u16* vth   = (u16*)alloc((size_t)BATCH*HID*SEQ*2);
    float* gate= (float*)alloc((size_t)ROWS*HID*4);

    prep_split<<<(HID2*DIM + QKD*DIM)/256, 256, 0, stream>>>(Wh, Wqk, whth, whtl, wqkth, wqktl);
    ln_kernel<<<ROWS/4, 256, 0, stream>>>(x, ln_g, ln_b, nh, nl);
    gemm_h<<<dim3(HID2/128, ROWS/128), 256, 0, stream>>>(nh, nl, whth, whtl, bh, vth, gate);
    gemm_qk<<<ROWS/128, 256, 0, stream>>>(nh, nl, wqkth, wqktl, bqk, gamma, beta, qh, ql, kh, kl);
    attn<<<512, 512, 0, stream>>>(qh, ql, kh, kl, vth, gate);
    wo_kernel<<<ROWS/4, 256, 0, stream>>>(gate, Wo, bo, out);
}

// Round 5
// 501.631 us; speedup vs baseline: 2.0959x; 1.2674x over previous
//
#include <hip/hip_runtime.h>
#include <stdint.h>

#define DIM   512
#define QKD   128
#define HID   1024
#define HID2  2048
#define OUTD  8
#define BATCH 4
#define SEQ   4096
#define ROWS  (BATCH*SEQ)   // 16384
#define LN_EPS 1e-5f

typedef unsigned short u16;
typedef unsigned int   u32;
typedef __bf16 bf16x8 __attribute__((ext_vector_type(8)));
typedef float  f32x4  __attribute__((ext_vector_type(4)));

// ---------- helpers ----------
__device__ inline u16 f2bf(float f){
    uint32_t u = __builtin_bit_cast(uint32_t, f);
    u += 0x7FFFu + ((u >> 16) & 1u);   // RNE
    return (u16)(u >> 16);
}
__device__ inline float bf2f(u16 h){
    uint32_t u = ((uint32_t)h) << 16;
    return __builtin_bit_cast(float, u);
}
__device__ inline void split_bf16(float x, u16 &hi, u16 &lo){
    hi = f2bf(x);
    float r = x - bf2f(hi);
    lo = f2bf(r);
}
__device__ inline bf16x8 ld_frag(const u16* p){
    uint4 r = *reinterpret_cast<const uint4*>(p);
    return __builtin_bit_cast(bf16x8, r);
}
__device__ inline f32x4 mfma16(bf16x8 a, bf16x8 b, f32x4 c){
    return __builtin_amdgcn_mfma_f32_16x16x32_bf16(a, b, c, 0, 0, 0);
}
__device__ inline float silu(float x){ return x / (1.f + expf(-x)); }

// ---------- P: split + transpose weights ----------
__global__ void prep_split(const float* __restrict__ Wh, const float* __restrict__ Wqk,
                           u16* whth, u16* whtl, u16* wqkth, u16* wqktl){
    int tid = blockIdx.x*256 + threadIdx.x;
    const int NWH = HID2*DIM;            // 1048576
    if (tid < NWH){
        int k = tid & (DIM-1);
        int n = tid >> 9;
        float w = Wh[(size_t)k*HID2 + n];
        u16 h,l; split_bf16(w,h,l);
        whth[tid]=h; whtl[tid]=l;
    } else {
        int t2 = tid - NWH;
        if (t2 < QKD*DIM){
            int k = t2 & (DIM-1);
            int n = t2 >> 9;
            float w = Wqk[(size_t)k*QKD + n];
            u16 h,l; split_bf16(w,h,l);
            wqkth[t2]=h; wqktl[t2]=l;
        }
    }
}

// ---------- K1: layernorm -> split bf16 ----------
__global__ __launch_bounds__(256) void ln_kernel(const float* __restrict__ x,
                                                 const float* __restrict__ g,
                                                 const float* __restrict__ b,
                                                 u16* nh, u16* nl){
    int wave = threadIdx.x >> 6, lane = threadIdx.x & 63;
    int row  = blockIdx.x*4 + wave;
    const float* xr = x + (size_t)row*DIM;
    float4 v0 = *(const float4*)(xr + lane*8);
    float4 v1 = *(const float4*)(xr + lane*8 + 4);
    float xs[8] = {v0.x,v0.y,v0.z,v0.w,v1.x,v1.y,v1.z,v1.w};
    float s = 0.f, q = 0.f;
    #pragma unroll
    for (int i=0;i<8;++i){ s += xs[i]; q += xs[i]*xs[i]; }
    #pragma unroll
    for (int m=1;m<64;m<<=1){ s += __shfl_xor(s,m,64); q += __shfl_xor(q,m,64); }
    float mean = s * (1.f/DIM);
    float var  = q * (1.f/DIM) - mean*mean;
    float rstd = rsqrtf(var + LN_EPS);
    float4 g0 = *(const float4*)(g + lane*8);
    float4 g1 = *(const float4*)(g + lane*8 + 4);
    float4 b0 = *(const float4*)(b + lane*8);
    float4 b1 = *(const float4*)(b + lane*8 + 4);
    float gs[8] = {g0.x,g0.y,g0.z,g0.w,g1.x,g1.y,g1.z,g1.w};
    float bs[8] = {b0.x,b0.y,b0.z,b0.w,b1.x,b1.y,b1.z,b1.w};
    u16 hh[8], ll[8];
    #pragma unroll
    for (int i=0;i<8;++i){
        float nv = (xs[i]-mean)*rstd*gs[i] + bs[i];
        split_bf16(nv, hh[i], ll[i]);
    }
    size_t o = (size_t)row*DIM + lane*8;
    *(uint4*)(nh + o) = *(uint4*)hh;
    *(uint4*)(nl + o) = *(uint4*)ll;
}

// ---------- K2: hidden = silu(n @ Wh + bh) -> v_f (fragment-major bf16) + gate ----------
__global__ __launch_bounds__(256,2) void gemm_h(
        const u16* __restrict__ nh, const u16* __restrict__ nl,
        const u16* __restrict__ bth, const u16* __restrict__ btl,
        const float* __restrict__ bh,
        u16* v_f, float* gate){
    __shared__ __align__(16) u16 At[2][128][40];
    __shared__ __align__(16) u16 Bt[2][128][40];
    int n0 = blockIdx.x * 128;
    int m0 = blockIdx.y * 128;
    int wave = threadIdx.x>>6, lane = threadIdx.x&63;
    int wr = wave>>1, wc = wave&1;
    f32x4 acc[4][4] = {};
    for (int ks=0; ks<16; ++ks){
        #pragma unroll
        for (int r=0;r<2;++r){
            int idx = r*256 + threadIdx.x;   // 0..511
            int row = idx>>2, ch = idx&3;
            size_t ga = (size_t)(m0+row)*DIM + ks*32 + ch*8;
            size_t gb = (size_t)(n0+row)*DIM + ks*32 + ch*8;
            *(uint4*)&At[0][row][ch*8] = *(const uint4*)(nh + ga);
            *(uint4*)&At[1][row][ch*8] = *(const uint4*)(nl + ga);
            *(uint4*)&Bt[0][row][ch*8] = *(const uint4*)(bth + gb);
            *(uint4*)&Bt[1][row][ch*8] = *(const uint4*)(btl + gb);
        }
        __syncthreads();
        bf16x8 Ah[4], Al[4];
        #pragma unroll
        for (int rf=0;rf<4;++rf){
            Ah[rf] = ld_frag(&At[0][wr*64 + rf*16 + (lane&15)][(lane>>4)*8]);
            Al[rf] = ld_frag(&At[1][wr*64 + rf*16 + (lane&15)][(lane>>4)*8]);
        }
        #pragma unroll
        for (int cf=0;cf<4;++cf){
            bf16x8 Bh = ld_frag(&Bt[0][wc*64 + cf*16 + (lane&15)][(lane>>4)*8]);
            bf16x8 Bl = ld_frag(&Bt[1][wc*64 + cf*16 + (lane&15)][(lane>>4)*8]);
            #pragma unroll
            for (int rf=0;rf<4;++rf){
                acc[rf][cf] = mfma16(Ah[rf], Bh, acc[rf][cf]);
                acc[rf][cf] = mfma16(Ah[rf], Bl, acc[rf][cf]);
                acc[rf][cf] = mfma16(Al[rf], Bh, acc[rf][cf]);
            }
        }
        __syncthreads();
    }
    #pragma unroll
    for (int rf=0;rf<4;++rf){
        #pragma unroll
        for (int cf=0;cf<4;++cf){
            #pragma unroll
            for (int r=0;r<4;++r){
                int row = m0 + wr*64 + rf*16 + (lane>>4)*4 + r;
                int col = n0 + wc*64 + cf*16 + (lane&15);
                float h = acc[rf][cf][r] + bh[col];
                float s = silu(h);
                if (col < HID){
                    int b = row >> 12, i = row & (SEQ-1);
                    // v_f[b][i>>5][col>>4][lane][8]: lane=(d&15)+16*((i>>3)&3), e=i&7
                    size_t o = (((size_t)b*128 + (i>>5))*64 + (col>>4))*512
                             + (size_t)((col&15) + (((i>>3)&3)<<4))*8 + (i&7);
                    v_f[o] = f2bf(s);
                } else {
                    gate[(size_t)row*HID + (col - HID)] = s;
                }
            }
        }
    }
}

// ---------- K3: Z = silu(n @ Wqk + bqk); q (bf16 hi) + k (split hi/lo), frag-major ----------
// q_f: [it=row>>4][ks=col>>5][512]         lane=(row&15)+16*((col>>3)&3), e=col&7
// k_f: [it][ks][hl][512]                   same lane/e mapping
__global__ __launch_bounds__(256,2) void gemm_qk(
        const u16* __restrict__ nh, const u16* __restrict__ nl,
        const u16* __restrict__ bth, const u16* __restrict__ btl,
        const float* __restrict__ bqk, const float* __restrict__ gamma,
        const float* __restrict__ beta,
        u16* q_f, u16* k_f){
    __shared__ __align__(16) u16 At[2][128][40];
    __shared__ __align__(16) u16 Bt[2][128][40];
    int m0 = blockIdx.x * 128;
    int wave = threadIdx.x>>6, lane = threadIdx.x&63;
    int wr = wave>>1, wc = wave&1;
    f32x4 acc[4][4] = {};
    for (int ks=0; ks<16; ++ks){
        #pragma unroll
        for (int r=0;r<2;++r){
            int idx = r*256 + threadIdx.x;
            int row = idx>>2, ch = idx&3;
            size_t ga = (size_t)(m0+row)*DIM + ks*32 + ch*8;
            size_t gb = (size_t)row*DIM + ks*32 + ch*8;   // n0 = 0, N=128
            *(uint4*)&At[0][row][ch*8] = *(const uint4*)(nh + ga);
            *(uint4*)&At[1][row][ch*8] = *(const uint4*)(nl + ga);
            *(uint4*)&Bt[0][row][ch*8] = *(const uint4*)(bth + gb);
            *(uint4*)&Bt[1][row][ch*8] = *(const uint4*)(btl + gb);
        }
        __syncthreads();
        bf16x8 Ah[4], Al[4];
        #pragma unroll
        for (int rf=0;rf<4;++rf){
            Ah[rf] = ld_frag(&At[0][wr*64 + rf*16 + (lane&15)][(lane>>4)*8]);
            Al[rf] = ld_frag(&At[1][wr*64 + rf*16 + (lane&15)][(lane>>4)*8]);
        }
        #pragma unroll
        for (int cf=0;cf<4;++cf){
            bf16x8 Bh = ld_frag(&Bt[0][wc*64 + cf*16 + (lane&15)][(lane>>4)*8]);
            bf16x8 Bl = ld_frag(&Bt[1][wc*64 + cf*16 + (lane&15)][(lane>>4)*8]);
            #pragma unroll
            for (int rf=0;rf<4;++rf){
                acc[rf][cf] = mfma16(Ah[rf], Bh, acc[rf][cf]);
                acc[rf][cf] = mfma16(Ah[rf], Bl, acc[rf][cf]);
                acc[rf][cf] = mfma16(Al[rf], Bh, acc[rf][cf]);
            }
        }
        __syncthreads();
    }
    #pragma unroll
    for (int rf=0;rf<4;++rf){
        #pragma unroll
        for (int cf=0;cf<4;++cf){
            #pragma unroll
            for (int r=0;r<4;++r){
                int row = m0 + wr*64 + rf*16 + (lane>>4)*4 + r;
                int col = wc*64 + cf*16 + (lane&15);
                float z = silu(acc[rf][cf][r] + bqk[col]);
                float qv = z*gamma[col]       + beta[col];
                float kv = z*gamma[QKD + col] + beta[QKD + col];
                size_t lane_e = (size_t)((row&15) + (((col>>3)&3)<<4))*8 + (col&7);
                size_t it4ks  = (size_t)(row>>4)*4 + (col>>5);
                q_f[it4ks*512 + lane_e] = f2bf(qv);
                u16 h_, l_;
                split_bf16(kv, h_, l_);
                k_f[(it4ks*2    )*512 + lane_e] = h_;
                k_f[(it4ks*2 + 1)*512 + lane_e] = l_;
            }
        }
    }
}

// ---------- K4: fused squared-relu attention ----------
// grid = 512 blocks: xcd=bid&7 -> (batch=xcd>>1, dhalf=xcd&1), qt=bid>>3 (64 q rows).
// 512 threads, 8 waves: fr=w>>2 (32 q-rows), fc=w&3 (16 j-cols). KV tile = 64.
// K,V direct global->reg from fragment-major buffers; only A goes through LDS
// (pitch 72, double-buffered, ONE barrier per kt). q bf16, k split hi+lo.
__global__ __launch_bounds__(512,2) void attn(
        const u16* __restrict__ q_f, const u16* __restrict__ k_f,
        const u16* __restrict__ v_f, float* gate){
    __shared__ __align__(16) u16 At[2][64*72];
    const int bid = blockIdx.x, xcd = bid & 7;
    const int batch = xcd >> 1, dhalf = xcd & 1, qt = bid >> 3;
    const int i0 = qt * 64;
    const int w = threadIdx.x >> 6, lane = threadIdx.x & 63;
    const int fr = w >> 2, fc = w & 3;

    // persistent Q fragments (bf16 hi only): wave's 32 q-rows = 2 it-tiles
    bf16x8 qf[2][4];
    {
        int itq = batch*256 + qt*4 + fr*2;      // SEQ/16 = 256 its per batch
        #pragma unroll
        for (int q2=0;q2<2;++q2)
        #pragma unroll
        for (int ks=0;ks<4;++ks)
            qf[q2][ks] = ld_frag(q_f + ((size_t)(itq+q2)*4 + ks)*512 + lane*8);
    }

    f32x4 acc[4][4] = {};   // 64 q-rows x 64 d-cols per wave

    for (int kt=0; kt<64; ++kt){
        // ---- K fragments (hi+lo), direct from global, coalesced 1KB frags ----
        int itk = batch*256 + kt*4 + fc;        // CORRECT stride: 256 its/batch
        bf16x8 kfh[4], kfl[4];
        #pragma unroll
        for (int ks=0;ks<4;++ks){
            kfh[ks] = ld_frag(k_f + (((size_t)itk*4 + ks)*2 + 0)*512 + lane*8);
            kfl[ks] = ld_frag(k_f + (((size_t)itk*4 + ks)*2 + 1)*512 + lane*8);
        }
        // ---- S = q.k^T : 2-term split (q bf16, k exact) ----
        f32x4 sacc[2] = {};
        #pragma unroll
        for (int ks=0;ks<4;++ks){
            #pragma unroll
            for (int q2=0;q2<2;++q2){
                sacc[q2] = mfma16(qf[q2][ks], kfh[ks], sacc[q2]);
                sacc[q2] = mfma16(qf[q2][ks], kfl[ks], sacc[q2]);
            }
        }
        // ---- A = bf16(relu(S)^2) -> LDS (pitch 72, double-buffered) ----
        u16* Ab = At[kt & 1];
        #pragma unroll
        for (int q2=0;q2<2;++q2){
            #pragma unroll
            for (int r=0;r<4;++r){
                float s = sacc[q2][r];
                s = s > 0.f ? s*s : 0.f;
                int q = fr*32 + q2*16 + (lane>>4)*4 + r;
                int j = fc*16 + (lane&15);
                Ab[q*72 + j] = f2bf(s);
            }
        }
        // ---- V fragments for this kt (issue before barrier, consume after) ----
        bf16x8 vb[2][4];
        #pragma unroll
        for (int kk=0;kk<2;++kk)
        #pragma unroll
        for (int dc=0;dc<4;++dc)
            vb[kk][dc] = ld_frag(v_f + (((size_t)(batch*128 + kt*2 + kk))*64
                                        + dhalf*32 + w*4 + dc)*512 + lane*8);
        __syncthreads();   // A visible to all waves; vb/kf drained
        // ---- PV: acc += A @ v on wave's 64-d slice ----
        #pragma unroll
        for (int kk=0;kk<2;++kk){
            #pragma unroll
            for (int qr=0;qr<4;++qr){
                bf16x8 af = ld_frag(&Ab[(qr*16 + (lane&15))*72 + kk*32 + (lane>>4)*8]);
                #pragma unroll
                for (int dc=0;dc<4;++dc)
                    acc[qr][dc] = mfma16(af, vb[kk][dc], acc[qr][dc]);
            }
        }
    }
    // ---- epilogue: gate <- V * gate * 2^-24 ----
    #pragma unroll
    for (int qr=0; qr<4; ++qr){
        #pragma unroll
        for (int dc=0; dc<4; ++dc){
            #pragma unroll
            for (int r=0; r<4; ++r){
                int i = i0 + qr*16 + (lane>>4)*4 + r;
                int d = dhalf*512 + w*64 + dc*16 + (lane&15);
                size_t go = ((size_t)(batch*SEQ + i))*HID + d;
                float g = gate[go];
                gate[go] = acc[qr][dc][r] * g * 0x1p-24f;
            }
        }
    }
}

// ---------- K5: out = Vg @ Wo + bo ----------
__global__ __launch_bounds__(256) void wo_kernel(const float* __restrict__ vg,
                                                 const float* __restrict__ Wo,
                                                 const float* __restrict__ bo,
                                                 float* out){
    int wave = threadIdx.x>>6, lane = threadIdx.x&63;
    int row  = blockIdx.x*4 + wave;
    const float* vr = vg + (size_t)row*HID;
    float po[8] = {};
    #pragma unroll
    for (int c=0;c<4;++c){
        float4 v = *(const float4*)(vr + c*256 + lane*4);
        float vv[4] = {v.x, v.y, v.z, v.w};
        #pragma unroll
        for (int e=0;e<4;++e){
            int col = c*256 + lane*4 + e;
            float4 w0 = *(const float4*)(Wo + (size_t)col*8);
            float4 w1 = *(const float4*)(Wo + (size_t)col*8 + 4);
            po[0] += vv[e]*w0.x; po[1] += vv[e]*w0.y; po[2] += vv[e]*w0.z; po[3] += vv[e]*w0.w;
            po[4] += vv[e]*w1.x; po[5] += vv[e]*w1.y; po[6] += vv[e]*w1.z; po[7] += vv[e]*w1.w;
        }
    }
    #pragma unroll
    for (int m=1;m<64;m<<=1){
        #pragma unroll
        for (int o=0;o<8;++o) po[o] += __shfl_xor(po[o], m, 64);
    }
    if (lane == 0){
        #pragma unroll
        for (int o=0;o<8;++o) out[(size_t)row*8 + o] = po[o] + bo[o];
    }
}

// ---------- launch ----------
extern "C" void kernel_launch(void* const* d_in, const int* in_sizes, int n_in,
                              void* d_out, int out_size, void* d_ws, size_t ws_size,
                              hipStream_t stream){
    const float* x    = (const float*)d_in[0];
    const float* ln_g = (const float*)d_in[1];
    const float* ln_b = (const float*)d_in[2];
    const float* Wh   = (const float*)d_in[3];
    const float* bh   = (const float*)d_in[4];
    const float* Wqk  = (const float*)d_in[5];
    const float* bqk  = (const float*)d_in[6];
    const float* gamma= (const float*)d_in[7];
    const float* beta = (const float*)d_in[8];
    const float* Wo   = (const float*)d_in[9];
    const float* bo   = (const float*)d_in[10];
    float* out = (float*)d_out;

    char* w = (char*)d_ws;
    auto alloc = [&](size_t bytes)->char*{
        char* p = w; w += (bytes + 255) & ~(size_t)255; return p;
    };
    u16* nh    = (u16*)alloc((size_t)ROWS*DIM*2);
    u16* nl    = (u16*)alloc((size_t)ROWS*DIM*2);
    u16* whth  = (u16*)alloc((size_t)HID2*DIM*2);
    u16* whtl  = (u16*)alloc((size_t)HID2*DIM*2);
    u16* wqkth = (u16*)alloc((size_t)QKD*DIM*2);
    u16* wqktl = (u16*)alloc((size_t)QKD*DIM*2);
    u16* q_f   = (u16*)alloc((size_t)ROWS*QKD*2);      // hi only, fragment-major
    u16* k_f   = (u16*)alloc((size_t)ROWS*QKD*2*2);    // hi+lo, fragment-major
    u16* v_f   = (u16*)alloc((size_t)BATCH*HID*SEQ*2); // hi only, fragment-major
    float* gate= (float*)alloc((size_t)ROWS*HID*4);

    prep_split<<<(HID2*DIM + QKD*DIM)/256, 256, 0, stream>>>(Wh, Wqk, whth, whtl, wqkth, wqktl);
    ln_kernel<<<ROWS/4, 256, 0, stream>>>(x, ln_g, ln_b, nh, nl);
    gemm_h<<<dim3(HID2/128, ROWS/128), 256, 0, stream>>>(nh, nl, whth, whtl, bh, v_f, gate);
    gemm_qk<<<ROWS/128, 256, 0, stream>>>(nh, nl, wqkth, wqktl, bqk, gamma, beta, q_f, k_f);
    attn<<<512, 512, 0, stream>>>(q_f, k_f, v_f, gate);
    wo_kernel<<<ROWS/4, 256, 0, stream>>>(gate, Wo, bo, out);
}

// Round 6
// 459.822 us; speedup vs baseline: 2.2865x; 1.0909x over previous
//
#include <hip/hip_runtime.h>
#include <stdint.h>

#define DIM   512
#define QKD   128
#define HID   1024
#define HID2  2048
#define OUTD  8
#define BATCH 4
#define SEQ   4096
#define ROWS  (BATCH*SEQ)   // 16384
#define LN_EPS 1e-5f

typedef unsigned short u16;
typedef unsigned int   u32;
typedef __bf16 bf16x8 __attribute__((ext_vector_type(8)));
typedef float  f32x4  __attribute__((ext_vector_type(4)));

// ---------- helpers ----------
__device__ inline u16 f2bf(float f){
    uint32_t u = __builtin_bit_cast(uint32_t, f);
    u += 0x7FFFu + ((u >> 16) & 1u);   // RNE
    return (u16)(u >> 16);
}
__device__ inline float bf2f(u16 h){
    uint32_t u = ((uint32_t)h) << 16;
    return __builtin_bit_cast(float, u);
}
__device__ inline void split_bf16(float x, u16 &hi, u16 &lo){
    hi = f2bf(x);
    float r = x - bf2f(hi);
    lo = f2bf(r);
}
__device__ inline bf16x8 ld_frag(const u16* p){
    uint4 r = *reinterpret_cast<const uint4*>(p);
    return __builtin_bit_cast(bf16x8, r);
}
__device__ inline f32x4 mfma16(bf16x8 a, bf16x8 b, f32x4 c){
    return __builtin_amdgcn_mfma_f32_16x16x32_bf16(a, b, c, 0, 0, 0);
}
__device__ inline float silu(float x){ return x / (1.f + expf(-x)); }

// ---------- P: split + transpose weights ----------
__global__ void prep_split(const float* __restrict__ Wh, const float* __restrict__ Wqk,
                           u16* whth, u16* whtl, u16* wqkth, u16* wqktl){
    int tid = blockIdx.x*256 + threadIdx.x;
    const int NWH = HID2*DIM;            // 1048576
    if (tid < NWH){
        int k = tid & (DIM-1);
        int n = tid >> 9;
        float w = Wh[(size_t)k*HID2 + n];
        u16 h,l; split_bf16(w,h,l);
        whth[tid]=h; whtl[tid]=l;
    } else {
        int t2 = tid - NWH;
        if (t2 < QKD*DIM){
            int k = t2 & (DIM-1);
            int n = t2 >> 9;
            float w = Wqk[(size_t)k*QKD + n];
            u16 h,l; split_bf16(w,h,l);
            wqkth[t2]=h; wqktl[t2]=l;
        }
    }
}

// ---------- K1: layernorm -> split bf16 ----------
__global__ __launch_bounds__(256) void ln_kernel(const float* __restrict__ x,
                                                 const float* __restrict__ g,
                                                 const float* __restrict__ b,
                                                 u16* nh, u16* nl){
    int wave = threadIdx.x >> 6, lane = threadIdx.x & 63;
    int row  = blockIdx.x*4 + wave;
    const float* xr = x + (size_t)row*DIM;
    float4 v0 = *(const float4*)(xr + lane*8);
    float4 v1 = *(const float4*)(xr + lane*8 + 4);
    float xs[8] = {v0.x,v0.y,v0.z,v0.w,v1.x,v1.y,v1.z,v1.w};
    float s = 0.f, q = 0.f;
    #pragma unroll
    for (int i=0;i<8;++i){ s += xs[i]; q += xs[i]*xs[i]; }
    #pragma unroll
    for (int m=1;m<64;m<<=1){ s += __shfl_xor(s,m,64); q += __shfl_xor(q,m,64); }
    float mean = s * (1.f/DIM);
    float var  = q * (1.f/DIM) - mean*mean;
    float rstd = rsqrtf(var + LN_EPS);
    float4 g0 = *(const float4*)(g + lane*8);
    float4 g1 = *(const float4*)(g + lane*8 + 4);
    float4 b0 = *(const float4*)(b + lane*8);
    float4 b1 = *(const float4*)(b + lane*8 + 4);
    float gs[8] = {g0.x,g0.y,g0.z,g0.w,g1.x,g1.y,g1.z,g1.w};
    float bs[8] = {b0.x,b0.y,b0.z,b0.w,b1.x,b1.y,b1.z,b1.w};
    u16 hh[8], ll[8];
    #pragma unroll
    for (int i=0;i<8;++i){
        float nv = (xs[i]-mean)*rstd*gs[i] + bs[i];
        split_bf16(nv, hh[i], ll[i]);
    }
    size_t o = (size_t)row*DIM + lane*8;
    *(uint4*)(nh + o) = *(uint4*)hh;
    *(uint4*)(nl + o) = *(uint4*)ll;
}

// ---------- K2: hidden = silu(n @ Wh + bh) -> v_f (fragment-major bf16) + gate ----------
__global__ __launch_bounds__(256,2) void gemm_h(
        const u16* __restrict__ nh, const u16* __restrict__ nl,
        const u16* __restrict__ bth, const u16* __restrict__ btl,
        const float* __restrict__ bh,
        u16* v_f, float* gate){
    __shared__ __align__(16) u16 At[2][128][40];
    __shared__ __align__(16) u16 Bt[2][128][40];
    int n0 = blockIdx.x * 128;
    int m0 = blockIdx.y * 128;
    int wave = threadIdx.x>>6, lane = threadIdx.x&63;
    int wr = wave>>1, wc = wave&1;
    f32x4 acc[4][4] = {};
    for (int ks=0; ks<16; ++ks){
        #pragma unroll
        for (int r=0;r<2;++r){
            int idx = r*256 + threadIdx.x;   // 0..511
            int row = idx>>2, ch = idx&3;
            size_t ga = (size_t)(m0+row)*DIM + ks*32 + ch*8;
            size_t gb = (size_t)(n0+row)*DIM + ks*32 + ch*8;
            *(uint4*)&At[0][row][ch*8] = *(const uint4*)(nh + ga);
            *(uint4*)&At[1][row][ch*8] = *(const uint4*)(nl + ga);
            *(uint4*)&Bt[0][row][ch*8] = *(const uint4*)(bth + gb);
            *(uint4*)&Bt[1][row][ch*8] = *(const uint4*)(btl + gb);
        }
        __syncthreads();
        bf16x8 Ah[4], Al[4];
        #pragma unroll
        for (int rf=0;rf<4;++rf){
            Ah[rf] = ld_frag(&At[0][wr*64 + rf*16 + (lane&15)][(lane>>4)*8]);
            Al[rf] = ld_frag(&At[1][wr*64 + rf*16 + (lane&15)][(lane>>4)*8]);
        }
        #pragma unroll
        for (int cf=0;cf<4;++cf){
            bf16x8 Bh = ld_frag(&Bt[0][wc*64 + cf*16 + (lane&15)][(lane>>4)*8]);
            bf16x8 Bl = ld_frag(&Bt[1][wc*64 + cf*16 + (lane&15)][(lane>>4)*8]);
            #pragma unroll
            for (int rf=0;rf<4;++rf){
                acc[rf][cf] = mfma16(Ah[rf], Bh, acc[rf][cf]);
                acc[rf][cf] = mfma16(Ah[rf], Bl, acc[rf][cf]);
                acc[rf][cf] = mfma16(Al[rf], Bh, acc[rf][cf]);
            }
        }
        __syncthreads();
    }
    #pragma unroll
    for (int rf=0;rf<4;++rf){
        #pragma unroll
        for (int cf=0;cf<4;++cf){
            #pragma unroll
            for (int r=0;r<4;++r){
                int row = m0 + wr*64 + rf*16 + (lane>>4)*4 + r;
                int col = n0 + wc*64 + cf*16 + (lane&15);
                float h = acc[rf][cf][r] + bh[col];
                float s = silu(h);
                if (col < HID){
                    int b = row >> 12, i = row & (SEQ-1);
                    // v_f[b][i>>5][col>>4][lane][8]: lane=(d&15)+16*((i>>3)&3), e=i&7
                    size_t o = (((size_t)b*128 + (i>>5))*64 + (col>>4))*512
                             + (size_t)((col&15) + (((i>>3)&3)<<4))*8 + (i&7);
                    v_f[o] = f2bf(s);
                } else {
                    gate[(size_t)row*HID + (col - HID)] = s;
                }
            }
        }
    }
}

// ---------- K3: Z = silu(n @ Wqk + bqk); q,k -> plain bf16, fragment-major ----------
// q_f/k_f: [it=row>>4][ks=col>>5][512]   lane=(row&15)+16*((col>>3)&3), e=col&7
__global__ __launch_bounds__(256,2) void gemm_qk(
        const u16* __restrict__ nh, const u16* __restrict__ nl,
        const u16* __restrict__ bth, const u16* __restrict__ btl,
        const float* __restrict__ bqk, const float* __restrict__ gamma,
        const float* __restrict__ beta,
        u16* q_f, u16* k_f){
    __shared__ __align__(16) u16 At[2][128][40];
    __shared__ __align__(16) u16 Bt[2][128][40];
    int m0 = blockIdx.x * 128;
    int wave = threadIdx.x>>6, lane = threadIdx.x&63;
    int wr = wave>>1, wc = wave&1;
    f32x4 acc[4][4] = {};
    for (int ks=0; ks<16; ++ks){
        #pragma unroll
        for (int r=0;r<2;++r){
            int idx = r*256 + threadIdx.x;
            int row = idx>>2, ch = idx&3;
            size_t ga = (size_t)(m0+row)*DIM + ks*32 + ch*8;
            size_t gb = (size_t)row*DIM + ks*32 + ch*8;   // n0 = 0, N=128
            *(uint4*)&At[0][row][ch*8] = *(const uint4*)(nh + ga);
            *(uint4*)&At[1][row][ch*8] = *(const uint4*)(nl + ga);
            *(uint4*)&Bt[0][row][ch*8] = *(const uint4*)(bth + gb);
            *(uint4*)&Bt[1][row][ch*8] = *(const uint4*)(btl + gb);
        }
        __syncthreads();
        bf16x8 Ah[4], Al[4];
        #pragma unroll
        for (int rf=0;rf<4;++rf){
            Ah[rf] = ld_frag(&At[0][wr*64 + rf*16 + (lane&15)][(lane>>4)*8]);
            Al[rf] = ld_frag(&At[1][wr*64 + rf*16 + (lane&15)][(lane>>4)*8]);
        }
        #pragma unroll
        for (int cf=0;cf<4;++cf){
            bf16x8 Bh = ld_frag(&Bt[0][wc*64 + cf*16 + (lane&15)][(lane>>4)*8]);
            bf16x8 Bl = ld_frag(&Bt[1][wc*64 + cf*16 + (lane&15)][(lane>>4)*8]);
            #pragma unroll
            for (int rf=0;rf<4;++rf){
                acc[rf][cf] = mfma16(Ah[rf], Bh, acc[rf][cf]);
                acc[rf][cf] = mfma16(Ah[rf], Bl, acc[rf][cf]);
                acc[rf][cf] = mfma16(Al[rf], Bh, acc[rf][cf]);
            }
        }
        __syncthreads();
    }
    #pragma unroll
    for (int rf=0;rf<4;++rf){
        #pragma unroll
        for (int cf=0;cf<4;++cf){
            #pragma unroll
            for (int r=0;r<4;++r){
                int row = m0 + wr*64 + rf*16 + (lane>>4)*4 + r;
                int col = wc*64 + cf*16 + (lane&15);
                float z = silu(acc[rf][cf][r] + bqk[col]);
                float qv = z*gamma[col]       + beta[col];
                float kv = z*gamma[QKD + col] + beta[QKD + col];
                size_t lane_e = (size_t)((row&15) + (((col>>3)&3)<<4))*8 + (col&7);
                size_t it4ks  = (size_t)(row>>4)*4 + (col>>5);
                q_f[it4ks*512 + lane_e] = f2bf(qv);
                k_f[it4ks*512 + lane_e] = f2bf(kv);
            }
        }
    }
}

// ---------- K4: fused squared-relu attention ----------
// grid = 512 blocks: xcd=bid&7 -> (batch=xcd>>1, dhalf=xcd&1), qt=bid>>3 (64 q rows).
// 512 threads, 8 waves: fr=w>>2 (32 q-rows), fc=w&3 (16 j-cols). KV tile = 64.
// q,k,v all plain bf16, direct global->reg, fragment-major; A via LDS (pitch 72,
// double-buffered, ONE barrier per kt). q reloaded per kt (L1-resident) to keep
// VGPR<=64 so total regs (incl 64 acc AGPRs) fit 128 -> 2 blocks/CU.
__global__ __launch_bounds__(512,4) void attn(
        const u16* __restrict__ q_f, const u16* __restrict__ k_f,
        const u16* __restrict__ v_f, float* gate){
    __shared__ __align__(16) u16 At[2][64*72];
    const int bid = blockIdx.x, xcd = bid & 7;
    const int batch = xcd >> 1, dhalf = xcd & 1, qt = bid >> 3;
    const int i0 = qt * 64;
    const int w = threadIdx.x >> 6, lane = threadIdx.x & 63;
    const int fr = w >> 2, fc = w & 3;

    f32x4 acc[4][4] = {};   // 64 q-rows x 64 d-cols per wave (64 AGPRs)

    const int itq = batch*256 + qt*4 + fr*2;   // SEQ/16 = 256 its per batch

    for (int kt=0; kt<64; ++kt){
        // ---- K + Q fragments for this kt (transient, coalesced 1KB frags) ----
        const int itk = batch*256 + kt*4 + fc;
        bf16x8 kf[4], qf0[4], qf1[4];
        #pragma unroll
        for (int ks=0;ks<4;++ks){
            kf[ks]  = ld_frag(k_f + ((size_t)itk*4 + ks)*512 + lane*8);
            qf0[ks] = ld_frag(q_f + ((size_t)itq*4 + ks)*512 + lane*8);
            qf1[ks] = ld_frag(q_f + ((size_t)(itq+1)*4 + ks)*512 + lane*8);
        }
        // ---- S = q.k^T : single term (q,k bf16) ----
        f32x4 sacc[2] = {};
        #pragma unroll
        for (int ks=0;ks<4;++ks){
            sacc[0] = mfma16(qf0[ks], kf[ks], sacc[0]);
            sacc[1] = mfma16(qf1[ks], kf[ks], sacc[1]);
        }
        // ---- A = bf16(relu(S)^2) -> LDS (pitch 72, double-buffered) ----
        u16* Ab = At[kt & 1];
        #pragma unroll
        for (int q2=0;q2<2;++q2){
            #pragma unroll
            for (int r=0;r<4;++r){
                float s = sacc[q2][r];
                s = s > 0.f ? s*s : 0.f;
                int q = fr*32 + q2*16 + (lane>>4)*4 + r;
                int j = fc*16 + (lane&15);
                Ab[q*72 + j] = f2bf(s);
            }
        }
        // ---- V fragments for this kt (issue before barrier, consume after) ----
        bf16x8 vb[2][4];
        #pragma unroll
        for (int kk=0;kk<2;++kk)
        #pragma unroll
        for (int dc=0;dc<4;++dc)
            vb[kk][dc] = ld_frag(v_f + (((size_t)(batch*128 + kt*2 + kk))*64
                                        + dhalf*32 + w*4 + dc)*512 + lane*8);
        __syncthreads();   // A visible to all waves
        // ---- PV: acc += A @ v on wave's 64-d slice ----
        #pragma unroll
        for (int kk=0;kk<2;++kk){
            #pragma unroll
            for (int qr=0;qr<4;++qr){
                bf16x8 af = ld_frag(&Ab[(qr*16 + (lane&15))*72 + kk*32 + (lane>>4)*8]);
                #pragma unroll
                for (int dc=0;dc<4;++dc)
                    acc[qr][dc] = mfma16(af, vb[kk][dc], acc[qr][dc]);
            }
        }
    }
    // ---- epilogue: gate <- V * gate * 2^-24 ----
    #pragma unroll
    for (int qr=0; qr<4; ++qr){
        #pragma unroll
        for (int dc=0; dc<4; ++dc){
            #pragma unroll
            for (int r=0; r<4; ++r){
                int i = i0 + qr*16 + (lane>>4)*4 + r;
                int d = dhalf*512 + w*64 + dc*16 + (lane&15);
                size_t go = ((size_t)(batch*SEQ + i))*HID + d;
                float g = gate[go];
                gate[go] = acc[qr][dc][r] * g * 0x1p-24f;
            }
        }
    }
}

// ---------- K5: out = Vg @ Wo + bo ----------
__global__ __launch_bounds__(256) void wo_kernel(const float* __restrict__ vg,
                                                 const float* __restrict__ Wo,
                                                 const float* __restrict__ bo,
                                                 float* out){
    int wave = threadIdx.x>>6, lane = threadIdx.x&63;
    int row  = blockIdx.x*4 + wave;
    const float* vr = vg + (size_t)row*HID;
    float po[8] = {};
    #pragma unroll
    for (int c=0;c<4;++c){
        float4 v = *(const float4*)(vr + c*256 + lane*4);
        float vv[4] = {v.x, v.y, v.z, v.w};
        #pragma unroll
        for (int e=0;e<4;++e){
            int col = c*256 + lane*4 + e;
            float4 w0 = *(const float4*)(Wo + (size_t)col*8);
            float4 w1 = *(const float4*)(Wo + (size_t)col*8 + 4);
            po[0] += vv[e]*w0.x; po[1] += vv[e]*w0.y; po[2] += vv[e]*w0.z; po[3] += vv[e]*w0.w;
            po[4] += vv[e]*w1.x; po[5] += vv[e]*w1.y; po[6] += vv[e]*w1.z; po[7] += vv[e]*w1.w;
        }
    }
    #pragma unroll
    for (int m=1;m<64;m<<=1){
        #pragma unroll
        for (int o=0;o<8;++o) po[o] += __shfl_xor(po[o], m, 64);
    }
    if (lane == 0){
        #pragma unroll
        for (int o=0;o<8;++o) out[(size_t)row*8 + o] = po[o] + bo[o];
    }
}

// ---------- launch ----------
extern "C" void kernel_launch(void* const* d_in, const int* in_sizes, int n_in,
                              void* d_out, int out_size, void* d_ws, size_t ws_size,
                              hipStream_t stream){
    const float* x    = (const float*)d_in[0];
    const float* ln_g = (const float*)d_in[1];
    const float* ln_b = (const float*)d_in[2];
    const float* Wh   = (const float*)d_in[3];
    const float* bh   = (const float*)d_in[4];
    const float* Wqk  = (const float*)d_in[5];
    const float* bqk  = (const float*)d_in[6];
    const float* gamma= (const float*)d_in[7];
    const float* beta = (const float*)d_in[8];
    const float* Wo   = (const float*)d_in[9];
    const float* bo   = (const float*)d_in[10];
    float* out = (float*)d_out;

    char* w = (char*)d_ws;
    auto alloc = [&](size_t bytes)->char*{
        char* p = w; w += (bytes + 255) & ~(size_t)255; return p;
    };
    u16* nh    = (u16*)alloc((size_t)ROWS*DIM*2);
    u16* nl    = (u16*)alloc((size_t)ROWS*DIM*2);
    u16* whth  = (u16*)alloc((size_t)HID2*DIM*2);
    u16* whtl  = (u16*)alloc((size_t)HID2*DIM*2);
    u16* wqkth = (u16*)alloc((size_t)QKD*DIM*2);
    u16* wqktl = (u16*)alloc((size_t)QKD*DIM*2);
    u16* q_f   = (u16*)alloc((size_t)ROWS*QKD*2);      // bf16, fragment-major
    u16* k_f   = (u16*)alloc((size_t)ROWS*QKD*2);      // bf16, fragment-major
    u16* v_f   = (u16*)alloc((size_t)BATCH*HID*SEQ*2); // bf16, fragment-major
    float* gate= (float*)alloc((size_t)ROWS*HID*4);

    prep_split<<<(HID2*DIM + QKD*DIM)/256, 256, 0, stream>>>(Wh, Wqk, whth, whtl, wqkth, wqktl);
    ln_kernel<<<ROWS/4, 256, 0, stream>>>(x, ln_g, ln_b, nh, nl);
    gemm_h<<<dim3(HID2/128, ROWS/128), 256, 0, stream>>>(nh, nl, whth, whtl, bh, v_f, gate);
    gemm_qk<<<ROWS/128, 256, 0, stream>>>(nh, nl, wqkth, wqktl, bqk, gamma, beta, q_f, k_f);
    attn<<<512, 512, 0, stream>>>(q_f, k_f, v_f, gate);
    wo_kernel<<<ROWS/4, 256, 0, stream>>>(gate, Wo, bo, out);
}

// Round 7
// 385.962 us; speedup vs baseline: 2.7241x; 1.1914x over previous
//
#include <hip/hip_runtime.h>
#include <stdint.h>

#define DIM   512
#define QKD   128
#define HID   1024
#define HID2  2048
#define OUTD  8
#define BATCH 4
#define SEQ   4096
#define ROWS  (BATCH*SEQ)   // 16384
#define LN_EPS 1e-5f

typedef unsigned short u16;
typedef unsigned int   u32;
typedef __bf16 bf16x8 __attribute__((ext_vector_type(8)));
typedef float  f32x4  __attribute__((ext_vector_type(4)));

// ---------- helpers ----------
__device__ inline u16 f2bf(float f){
    uint32_t u = __builtin_bit_cast(uint32_t, f);
    u += 0x7FFFu + ((u >> 16) & 1u);   // RNE
    return (u16)(u >> 16);
}
__device__ inline float bf2f(u16 h){
    uint32_t u = ((uint32_t)h) << 16;
    return __builtin_bit_cast(float, u);
}
__device__ inline void split_bf16(float x, u16 &hi, u16 &lo){
    hi = f2bf(x);
    float r = x - bf2f(hi);
    lo = f2bf(r);
}
__device__ inline bf16x8 ld_frag(const u16* p){
    uint4 r = *reinterpret_cast<const uint4*>(p);
    return __builtin_bit_cast(bf16x8, r);
}
__device__ inline f32x4 mfma16(bf16x8 a, bf16x8 b, f32x4 c){
    return __builtin_amdgcn_mfma_f32_16x16x32_bf16(a, b, c, 0, 0, 0);
}
__device__ inline float silu(float x){ return x / (1.f + expf(-x)); }
// async global->LDS, 16B per lane; lds base wave-uniform (HW adds lane*16)
__device__ inline void gload_lds16(const u16* g, u16* l){
    __builtin_amdgcn_global_load_lds(
        (const __attribute__((address_space(1))) u32*)g,
        (__attribute__((address_space(3))) u32*)l, 16, 0, 0);
}

// ---------- P: split + transpose weights ----------
__global__ void prep_split(const float* __restrict__ Wh, const float* __restrict__ Wqk,
                           u16* whth, u16* whtl, u16* wqkth, u16* wqktl){
    int tid = blockIdx.x*256 + threadIdx.x;
    const int NWH = HID2*DIM;            // 1048576
    if (tid < NWH){
        int k = tid & (DIM-1);
        int n = tid >> 9;
        float w = Wh[(size_t)k*HID2 + n];
        u16 h,l; split_bf16(w,h,l);
        whth[tid]=h; whtl[tid]=l;
    } else {
        int t2 = tid - NWH;
        if (t2 < QKD*DIM){
            int k = t2 & (DIM-1);
            int n = t2 >> 9;
            float w = Wqk[(size_t)k*QKD + n];
            u16 h,l; split_bf16(w,h,l);
            wqkth[t2]=h; wqktl[t2]=l;
        }
    }
}

// ---------- K1: layernorm -> split bf16 ----------
__global__ __launch_bounds__(256) void ln_kernel(const float* __restrict__ x,
                                                 const float* __restrict__ g,
                                                 const float* __restrict__ b,
                                                 u16* nh, u16* nl){
    int wave = threadIdx.x >> 6, lane = threadIdx.x & 63;
    int row  = blockIdx.x*4 + wave;
    const float* xr = x + (size_t)row*DIM;
    float4 v0 = *(const float4*)(xr + lane*8);
    float4 v1 = *(const float4*)(xr + lane*8 + 4);
    float xs[8] = {v0.x,v0.y,v0.z,v0.w,v1.x,v1.y,v1.z,v1.w};
    float s = 0.f, q = 0.f;
    #pragma unroll
    for (int i=0;i<8;++i){ s += xs[i]; q += xs[i]*xs[i]; }
    #pragma unroll
    for (int m=1;m<64;m<<=1){ s += __shfl_xor(s,m,64); q += __shfl_xor(q,m,64); }
    float mean = s * (1.f/DIM);
    float var  = q * (1.f/DIM) - mean*mean;
    float rstd = rsqrtf(var + LN_EPS);
    float4 g0 = *(const float4*)(g + lane*8);
    float4 g1 = *(const float4*)(g + lane*8 + 4);
    float4 b0 = *(const float4*)(b + lane*8);
    float4 b1 = *(const float4*)(b + lane*8 + 4);
    float gs[8] = {g0.x,g0.y,g0.z,g0.w,g1.x,g1.y,g1.z,g1.w};
    float bs[8] = {b0.x,b0.y,b0.z,b0.w,b1.x,b1.y,b1.z,b1.w};
    u16 hh[8], ll[8];
    #pragma unroll
    for (int i=0;i<8;++i){
        float nv = (xs[i]-mean)*rstd*gs[i] + bs[i];
        split_bf16(nv, hh[i], ll[i]);
    }
    size_t o = (size_t)row*DIM + lane*8;
    *(uint4*)(nh + o) = *(uint4*)hh;
    *(uint4*)(nl + o) = *(uint4*)ll;
}

// ---------- K2: hidden = silu(n @ Wh + bh) -> v_f (fragment-major bf16) + gate ----------
__global__ __launch_bounds__(256,2) void gemm_h(
        const u16* __restrict__ nh, const u16* __restrict__ nl,
        const u16* __restrict__ bth, const u16* __restrict__ btl,
        const float* __restrict__ bh,
        u16* v_f, float* gate){
    __shared__ __align__(16) u16 At[2][128][40];
    __shared__ __align__(16) u16 Bt[2][128][40];
    int n0 = blockIdx.x * 128;
    int m0 = blockIdx.y * 128;
    int wave = threadIdx.x>>6, lane = threadIdx.x&63;
    int wr = wave>>1, wc = wave&1;
    f32x4 acc[4][4] = {};
    for (int ks=0; ks<16; ++ks){
        #pragma unroll
        for (int r=0;r<2;++r){
            int idx = r*256 + threadIdx.x;   // 0..511
            int row = idx>>2, ch = idx&3;
            size_t ga = (size_t)(m0+row)*DIM + ks*32 + ch*8;
            size_t gb = (size_t)(n0+row)*DIM + ks*32 + ch*8;
            *(uint4*)&At[0][row][ch*8] = *(const uint4*)(nh + ga);
            *(uint4*)&At[1][row][ch*8] = *(const uint4*)(nl + ga);
            *(uint4*)&Bt[0][row][ch*8] = *(const uint4*)(bth + gb);
            *(uint4*)&Bt[1][row][ch*8] = *(const uint4*)(btl + gb);
        }
        __syncthreads();
        bf16x8 Ah[4], Al[4];
        #pragma unroll
        for (int rf=0;rf<4;++rf){
            Ah[rf] = ld_frag(&At[0][wr*64 + rf*16 + (lane&15)][(lane>>4)*8]);
            Al[rf] = ld_frag(&At[1][wr*64 + rf*16 + (lane&15)][(lane>>4)*8]);
        }
        #pragma unroll
        for (int cf=0;cf<4;++cf){
            bf16x8 Bh = ld_frag(&Bt[0][wc*64 + cf*16 + (lane&15)][(lane>>4)*8]);
            bf16x8 Bl = ld_frag(&Bt[1][wc*64 + cf*16 + (lane&15)][(lane>>4)*8]);
            #pragma unroll
            for (int rf=0;rf<4;++rf){
                acc[rf][cf] = mfma16(Ah[rf], Bh, acc[rf][cf]);
                acc[rf][cf] = mfma16(Ah[rf], Bl, acc[rf][cf]);
                acc[rf][cf] = mfma16(Al[rf], Bh, acc[rf][cf]);
            }
        }
        __syncthreads();
    }
    #pragma unroll
    for (int rf=0;rf<4;++rf){
        #pragma unroll
        for (int cf=0;cf<4;++cf){
            #pragma unroll
            for (int r=0;r<4;++r){
                int row = m0 + wr*64 + rf*16 + (lane>>4)*4 + r;
                int col = n0 + wc*64 + cf*16 + (lane&15);
                float h = acc[rf][cf][r] + bh[col];
                float s = silu(h);
                if (col < HID){
                    int b = row >> 12, i = row & (SEQ-1);
                    // v_f[b][i>>5][col>>4][lane][8]: lane=(d&15)+16*((i>>3)&3), e=i&7
                    size_t o = (((size_t)b*128 + (i>>5))*64 + (col>>4))*512
                             + (size_t)((col&15) + (((i>>3)&3)<<4))*8 + (i&7);
                    v_f[o] = f2bf(s);
                } else {
                    gate[(size_t)row*HID + (col - HID)] = s;
                }
            }
        }
    }
}

// ---------- K3: Z = silu(n @ Wqk + bqk); q,k -> plain bf16, fragment-major ----------
// q_f/k_f: [it=row>>4][ks=col>>5][512]   lane=(row&15)+16*((col>>3)&3), e=col&7
__global__ __launch_bounds__(256,2) void gemm_qk(
        const u16* __restrict__ nh, const u16* __restrict__ nl,
        const u16* __restrict__ bth, const u16* __restrict__ btl,
        const float* __restrict__ bqk, const float* __restrict__ gamma,
        const float* __restrict__ beta,
        u16* q_f, u16* k_f){
    __shared__ __align__(16) u16 At[2][128][40];
    __shared__ __align__(16) u16 Bt[2][128][40];
    int m0 = blockIdx.x * 128;
    int wave = threadIdx.x>>6, lane = threadIdx.x&63;
    int wr = wave>>1, wc = wave&1;
    f32x4 acc[4][4] = {};
    for (int ks=0; ks<16; ++ks){
        #pragma unroll
        for (int r=0;r<2;++r){
            int idx = r*256 + threadIdx.x;
            int row = idx>>2, ch = idx&3;
            size_t ga = (size_t)(m0+row)*DIM + ks*32 + ch*8;
            size_t gb = (size_t)row*DIM + ks*32 + ch*8;   // n0 = 0, N=128
            *(uint4*)&At[0][row][ch*8] = *(const uint4*)(nh + ga);
            *(uint4*)&At[1][row][ch*8] = *(const uint4*)(nl + ga);
            *(uint4*)&Bt[0][row][ch*8] = *(const uint4*)(bth + gb);
            *(uint4*)&Bt[1][row][ch*8] = *(const uint4*)(btl + gb);
        }
        __syncthreads();
        bf16x8 Ah[4], Al[4];
        #pragma unroll
        for (int rf=0;rf<4;++rf){
            Ah[rf] = ld_frag(&At[0][wr*64 + rf*16 + (lane&15)][(lane>>4)*8]);
            Al[rf] = ld_frag(&At[1][wr*64 + rf*16 + (lane&15)][(lane>>4)*8]);
        }
        #pragma unroll
        for (int cf=0;cf<4;++cf){
            bf16x8 Bh = ld_frag(&Bt[0][wc*64 + cf*16 + (lane&15)][(lane>>4)*8]);
            bf16x8 Bl = ld_frag(&Bt[1][wc*64 + cf*16 + (lane&15)][(lane>>4)*8]);
            #pragma unroll
            for (int rf=0;rf<4;++rf){
                acc[rf][cf] = mfma16(Ah[rf], Bh, acc[rf][cf]);
                acc[rf][cf] = mfma16(Ah[rf], Bl, acc[rf][cf]);
                acc[rf][cf] = mfma16(Al[rf], Bh, acc[rf][cf]);
            }
        }
        __syncthreads();
    }
    #pragma unroll
    for (int rf=0;rf<4;++rf){
        #pragma unroll
        for (int cf=0;cf<4;++cf){
            #pragma unroll
            for (int r=0;r<4;++r){
                int row = m0 + wr*64 + rf*16 + (lane>>4)*4 + r;
                int col = wc*64 + cf*16 + (lane&15);
                float z = silu(acc[rf][cf][r] + bqk[col]);
                float qv = z*gamma[col]       + beta[col];
                float kv = z*gamma[QKD + col] + beta[QKD + col];
                size_t lane_e = (size_t)((row&15) + (((col>>3)&3)<<4))*8 + (col&7);
                size_t it4ks  = (size_t)(row>>4)*4 + (col>>5);
                q_f[it4ks*512 + lane_e] = f2bf(qv);
                k_f[it4ks*512 + lane_e] = f2bf(kv);
            }
        }
    }
}

// ---------- K4: fused squared-relu attention ----------
// grid = 256 blocks (1/CU): xcd=bid&7 -> (batch=xcd>>1, dhalf=xcd&1), qt=bid>>3 (0..31).
// 1024 threads, 16 waves. QTILE=128, KV=64, d-slice 512.
// Q staged ONCE in LDS (32KB). K staged per kt via global_load_lds dbuf (2x16KB),
// prefetched one kt ahead. V direct global->reg (read exactly once). A via LDS
// (pitch 72, dbuf). ONE barrier per kt.
// QK: wave w -> fr=w>>1 (16 q rows), fc=(w&1)*2+{0,1} (32 j). PV: wave owns 32 d.
__global__ __launch_bounds__(1024,4) void attn(
        const u16* __restrict__ q_f, const u16* __restrict__ k_f,
        const u16* __restrict__ v_f, float* gate){
    __shared__ __align__(16) u16 QL[16384];      // 128q x 128d frag-major
    __shared__ __align__(16) u16 KT[2][8192];    // dbuf: 64j x 128d frag-major
    __shared__ __align__(16) u16 AT[2][128*72];  // dbuf: A = relu(S)^2, pitch 72
    const int bid = blockIdx.x, xcd = bid & 7;
    const int batch = xcd >> 1, dhalf = xcd & 1, qt = bid >> 3;
    const int i0 = qt * 128;
    const int w = threadIdx.x >> 6, lane = threadIdx.x & 63;
    const int fr = w >> 1, fc2 = (w & 1) * 2;

    // ---- stage Q tile once: 32KB = 8 it-tiles, contiguous in q_f ----
    {
        size_t qbase = ((size_t)(batch*256 + qt*8))*4*512;
        #pragma unroll
        for (int c=0;c<2;++c){
            int idx = c*1024 + threadIdx.x;      // 0..2047 vec4s
            *(uint4*)&QL[idx*8] = *(const uint4*)(q_f + qbase + (size_t)idx*8);
        }
    }
    // ---- K staging: 16KB per kt, 16 waves x 1KB, async ----
    auto stageK = [&](int kt, int p){
        size_t kbase = ((size_t)(batch*256 + kt*4))*4*512;
        gload_lds16(k_f + kbase + (size_t)w*512 + lane*8, &KT[p][w*512]);
    };
    stageK(0, 0);
    __syncthreads();   // Q staged + KT[0] ready

    f32x4 acc[8][2] = {};   // 128 q-rows x 32 d-cols per wave (64 AGPRs)
    int p = 0;
    for (int kt=0; kt<64; ++kt){
        stageK((kt+1)&63, p^1);   // prefetch next K (drains at this kt's barrier)
        // ---- QK: S = q.k^T, wave does 16q x 32j (2 frags) ----
        f32x4 sacc[2] = {};
        #pragma unroll
        for (int ks=0;ks<4;++ks){
            bf16x8 qa = ld_frag(&QL[(fr*4 + ks)*512 + lane*8]);
            #pragma unroll
            for (int t=0;t<2;++t){
                bf16x8 kb = ld_frag(&KT[p][((fc2+t)*4 + ks)*512 + lane*8]);
                sacc[t] = mfma16(qa, kb, sacc[t]);
            }
        }
        // ---- A = bf16(relu(S)^2) -> LDS (pitch 72, dbuf) ----
        u16* Ab = AT[kt & 1];
        #pragma unroll
        for (int t=0;t<2;++t){
            #pragma unroll
            for (int r=0;r<4;++r){
                float s = sacc[t][r];
                s = s > 0.f ? s*s : 0.f;
                int q = fr*16 + (lane>>4)*4 + r;
                int j = (fc2+t)*16 + (lane&15);
                Ab[q*72 + j] = f2bf(s);
            }
        }
        // ---- V frags (read once; issue before barrier, consume after) ----
        bf16x8 vb[2][2];
        #pragma unroll
        for (int kk=0;kk<2;++kk)
        #pragma unroll
        for (int dc=0;dc<2;++dc)
            vb[kk][dc] = ld_frag(v_f + (((size_t)(batch*128 + kt*2 + kk))*64
                                        + dhalf*32 + w*2 + dc)*512 + lane*8);
        __syncthreads();   // A visible; K(kt+1) + V(kt) drained
        // ---- PV: acc += A @ v on wave's 32-d slice ----
        #pragma unroll
        for (int kk=0;kk<2;++kk){
            #pragma unroll
            for (int qr=0;qr<8;++qr){
                bf16x8 af = ld_frag(&Ab[(qr*16 + (lane&15))*72 + kk*32 + (lane>>4)*8]);
                #pragma unroll
                for (int dc=0;dc<2;++dc)
                    acc[qr][dc] = mfma16(af, vb[kk][dc], acc[qr][dc]);
            }
        }
        p ^= 1;
    }
    // ---- epilogue: gate <- V * gate * 2^-24 ----
    #pragma unroll
    for (int qr=0; qr<8; ++qr){
        #pragma unroll
        for (int dc=0; dc<2; ++dc){
            #pragma unroll
            for (int r=0; r<4; ++r){
                int i = i0 + qr*16 + (lane>>4)*4 + r;
                int d = dhalf*512 + w*32 + dc*16 + (lane&15);
                size_t go = ((size_t)(batch*SEQ + i))*HID + d;
                float g = gate[go];
                gate[go] = acc[qr][dc][r] * g * 0x1p-24f;
            }
        }
    }
}

// ---------- K5: out = Vg @ Wo + bo ----------
__global__ __launch_bounds__(256) void wo_kernel(const float* __restrict__ vg,
                                                 const float* __restrict__ Wo,
                                                 const float* __restrict__ bo,
                                                 float* out){
    int wave = threadIdx.x>>6, lane = threadIdx.x&63;
    int row  = blockIdx.x*4 + wave;
    const float* vr = vg + (size_t)row*HID;
    float po[8] = {};
    #pragma unroll
    for (int c=0;c<4;++c){
        float4 v = *(const float4*)(vr + c*256 + lane*4);
        float vv[4] = {v.x, v.y, v.z, v.w};
        #pragma unroll
        for (int e=0;e<4;++e){
            int col = c*256 + lane*4 + e;
            float4 w0 = *(const float4*)(Wo + (size_t)col*8);
            float4 w1 = *(const float4*)(Wo + (size_t)col*8 + 4);
            po[0] += vv[e]*w0.x; po[1] += vv[e]*w0.y; po[2] += vv[e]*w0.z; po[3] += vv[e]*w0.w;
            po[4] += vv[e]*w1.x; po[5] += vv[e]*w1.y; po[6] += vv[e]*w1.z; po[7] += vv[e]*w1.w;
        }
    }
    #pragma unroll
    for (int m=1;m<64;m<<=1){
        #pragma unroll
        for (int o=0;o<8;++o) po[o] += __shfl_xor(po[o], m, 64);
    }
    if (lane == 0){
        #pragma unroll
        for (int o=0;o<8;++o) out[(size_t)row*8 + o] = po[o] + bo[o];
    }
}

// ---------- launch ----------
extern "C" void kernel_launch(void* const* d_in, const int* in_sizes, int n_in,
                              void* d_out, int out_size, void* d_ws, size_t ws_size,
                              hipStream_t stream){
    const float* x    = (const float*)d_in[0];
    const float* ln_g = (const float*)d_in[1];
    const float* ln_b = (const float*)d_in[2];
    const float* Wh   = (const float*)d_in[3];
    const float* bh   = (const float*)d_in[4];
    const float* Wqk  = (const float*)d_in[5];
    const float* bqk  = (const float*)d_in[6];
    const float* gamma= (const float*)d_in[7];
    const float* beta = (const float*)d_in[8];
    const float* Wo   = (const float*)d_in[9];
    const float* bo   = (const float*)d_in[10];
    float* out = (float*)d_out;

    char* w = (char*)d_ws;
    auto alloc = [&](size_t bytes)->char*{
        char* p = w; w += (bytes + 255) & ~(size_t)255; return p;
    };
    u16* nh    = (u16*)alloc((size_t)ROWS*DIM*2);
    u16* nl    = (u16*)alloc((size_t)ROWS*DIM*2);
    u16* whth  = (u16*)alloc((size_t)HID2*DIM*2);
    u16* whtl  = (u16*)alloc((size_t)HID2*DIM*2);
    u16* wqkth = (u16*)alloc((size_t)QKD*DIM*2);
    u16* wqktl = (u16*)alloc((size_t)QKD*DIM*2);
    u16* q_f   = (u16*)alloc((size_t)ROWS*QKD*2);      // bf16, fragment-major
    u16* k_f   = (u16*)alloc((size_t)ROWS*QKD*2);      // bf16, fragment-major
    u16* v_f   = (u16*)alloc((size_t)BATCH*HID*SEQ*2); // bf16, fragment-major
    float* gate= (float*)alloc((size_t)ROWS*HID*4);

    prep_split<<<(HID2*DIM + QKD*DIM)/256, 256, 0, stream>>>(Wh, Wqk, whth, whtl, wqkth, wqktl);
    ln_kernel<<<ROWS/4, 256, 0, stream>>>(x, ln_g, ln_b, nh, nl);
    gemm_h<<<dim3(HID2/128, ROWS/128), 256, 0, stream>>>(nh, nl, whth, whtl, bh, v_f, gate);
    gemm_qk<<<ROWS/128, 256, 0, stream>>>(nh, nl, wqkth, wqktl, bqk, gamma, beta, q_f, k_f);
    attn<<<256, 1024, 0, stream>>>(q_f, k_f, v_f, gate);
    wo_kernel<<<ROWS/4, 256, 0, stream>>>(gate, Wo, bo, out);
}

// Round 8
// 365.649 us; speedup vs baseline: 2.8754x; 1.0556x over previous
//
#include <hip/hip_runtime.h>
#include <stdint.h>

#define DIM   512
#define QKD   128
#define HID   1024
#define HID2  2048
#define OUTD  8
#define BATCH 4
#define SEQ   4096
#define ROWS  (BATCH*SEQ)   // 16384
#define LN_EPS 1e-5f

typedef unsigned short u16;
typedef unsigned int   u32;
typedef __bf16 bf16x8 __attribute__((ext_vector_type(8)));
typedef float  f32x4  __attribute__((ext_vector_type(4)));

// ---------- helpers ----------
__device__ inline u16 f2bf(float f){
    uint32_t u = __builtin_bit_cast(uint32_t, f);
    u += 0x7FFFu + ((u >> 16) & 1u);   // RNE
    return (u16)(u >> 16);
}
__device__ inline float bf2f(u16 h){
    uint32_t u = ((uint32_t)h) << 16;
    return __builtin_bit_cast(float, u);
}
__device__ inline void split_bf16(float x, u16 &hi, u16 &lo){
    hi = f2bf(x);
    float r = x - bf2f(hi);
    lo = f2bf(r);
}
__device__ inline bf16x8 ld_frag(const u16* p){
    uint4 r = *reinterpret_cast<const uint4*>(p);
    return __builtin_bit_cast(bf16x8, r);
}
__device__ inline f32x4 mfma16(bf16x8 a, bf16x8 b, f32x4 c){
    return __builtin_amdgcn_mfma_f32_16x16x32_bf16(a, b, c, 0, 0, 0);
}
__device__ inline float silu(float x){ return x / (1.f + expf(-x)); }
// async global->LDS, 16B per lane; lds base wave-uniform (HW adds lane*16)
__device__ inline void gload_lds16(const u16* g, u16* l){
    __builtin_amdgcn_global_load_lds(
        (const __attribute__((address_space(1))) u32*)g,
        (__attribute__((address_space(3))) u32*)l, 16, 0, 0);
}

// ---------- P: split + transpose weights ----------
__global__ void prep_split(const float* __restrict__ Wh, const float* __restrict__ Wqk,
                           u16* whth, u16* whtl, u16* wqkth, u16* wqktl){
    int tid = blockIdx.x*256 + threadIdx.x;
    const int NWH = HID2*DIM;            // 1048576
    if (tid < NWH){
        int k = tid & (DIM-1);
        int n = tid >> 9;
        float w = Wh[(size_t)k*HID2 + n];
        u16 h,l; split_bf16(w,h,l);
        whth[tid]=h; whtl[tid]=l;
    } else {
        int t2 = tid - NWH;
        if (t2 < QKD*DIM){
            int k = t2 & (DIM-1);
            int n = t2 >> 9;
            float w = Wqk[(size_t)k*QKD + n];
            u16 h,l; split_bf16(w,h,l);
            wqkth[t2]=h; wqktl[t2]=l;
        }
    }
}

// ---------- K1: layernorm -> bf16 ----------
__global__ __launch_bounds__(256) void ln_kernel(const float* __restrict__ x,
                                                 const float* __restrict__ g,
                                                 const float* __restrict__ b,
                                                 u16* nh){
    int wave = threadIdx.x >> 6, lane = threadIdx.x & 63;
    int row  = blockIdx.x*4 + wave;
    const float* xr = x + (size_t)row*DIM;
    float4 v0 = *(const float4*)(xr + lane*8);
    float4 v1 = *(const float4*)(xr + lane*8 + 4);
    float xs[8] = {v0.x,v0.y,v0.z,v0.w,v1.x,v1.y,v1.z,v1.w};
    float s = 0.f, q = 0.f;
    #pragma unroll
    for (int i=0;i<8;++i){ s += xs[i]; q += xs[i]*xs[i]; }
    #pragma unroll
    for (int m=1;m<64;m<<=1){ s += __shfl_xor(s,m,64); q += __shfl_xor(q,m,64); }
    float mean = s * (1.f/DIM);
    float var  = q * (1.f/DIM) - mean*mean;
    float rstd = rsqrtf(var + LN_EPS);
    float4 g0 = *(const float4*)(g + lane*8);
    float4 g1 = *(const float4*)(g + lane*8 + 4);
    float4 b0 = *(const float4*)(b + lane*8);
    float4 b1 = *(const float4*)(b + lane*8 + 4);
    float gs[8] = {g0.x,g0.y,g0.z,g0.w,g1.x,g1.y,g1.z,g1.w};
    float bs[8] = {b0.x,b0.y,b0.z,b0.w,b1.x,b1.y,b1.z,b1.w};
    u16 hh[8];
    #pragma unroll
    for (int i=0;i<8;++i){
        float nv = (xs[i]-mean)*rstd*gs[i] + bs[i];
        hh[i] = f2bf(nv);
    }
    size_t o = (size_t)row*DIM + lane*8;
    *(uint4*)(nh + o) = *(uint4*)hh;
}

// ---------- K2: hidden = silu(bf16(n) @ (Wh_hi+Wh_lo) + bh) -> v_f + gate ----------
__global__ __launch_bounds__(256,2) void gemm_h(
        const u16* __restrict__ nh,
        const u16* __restrict__ bth, const u16* __restrict__ btl,
        const float* __restrict__ bh,
        u16* v_f, float* gate){
    __shared__ __align__(16) u16 At[128][40];
    __shared__ __align__(16) u16 Bt[2][128][40];
    int n0 = blockIdx.x * 128;
    int m0 = blockIdx.y * 128;
    int wave = threadIdx.x>>6, lane = threadIdx.x&63;
    int wr = wave>>1, wc = wave&1;
    f32x4 acc[4][4] = {};
    for (int ks=0; ks<16; ++ks){
        #pragma unroll
        for (int r=0;r<2;++r){
            int idx = r*256 + threadIdx.x;   // 0..511
            int row = idx>>2, ch = idx&3;
            size_t ga = (size_t)(m0+row)*DIM + ks*32 + ch*8;
            size_t gb = (size_t)(n0+row)*DIM + ks*32 + ch*8;
            *(uint4*)&At[row][ch*8]    = *(const uint4*)(nh + ga);
            *(uint4*)&Bt[0][row][ch*8] = *(const uint4*)(bth + gb);
            *(uint4*)&Bt[1][row][ch*8] = *(const uint4*)(btl + gb);
        }
        __syncthreads();
        bf16x8 Ah[4];
        #pragma unroll
        for (int rf=0;rf<4;++rf)
            Ah[rf] = ld_frag(&At[wr*64 + rf*16 + (lane&15)][(lane>>4)*8]);
        #pragma unroll
        for (int cf=0;cf<4;++cf){
            bf16x8 Bh = ld_frag(&Bt[0][wc*64 + cf*16 + (lane&15)][(lane>>4)*8]);
            bf16x8 Bl = ld_frag(&Bt[1][wc*64 + cf*16 + (lane&15)][(lane>>4)*8]);
            #pragma unroll
            for (int rf=0;rf<4;++rf){
                acc[rf][cf] = mfma16(Ah[rf], Bh, acc[rf][cf]);
                acc[rf][cf] = mfma16(Ah[rf], Bl, acc[rf][cf]);
            }
        }
        __syncthreads();
    }
    #pragma unroll
    for (int rf=0;rf<4;++rf){
        #pragma unroll
        for (int cf=0;cf<4;++cf){
            #pragma unroll
            for (int r=0;r<4;++r){
                int row = m0 + wr*64 + rf*16 + (lane>>4)*4 + r;
                int col = n0 + wc*64 + cf*16 + (lane&15);
                float h = acc[rf][cf][r] + bh[col];
                float s = silu(h);
                if (col < HID){
                    int b = row >> 12, i = row & (SEQ-1);
                    // v_f[b][i>>5][col>>4][lane][8]: lane=(d&15)+16*((i>>3)&3), e=i&7
                    size_t o = (((size_t)b*128 + (i>>5))*64 + (col>>4))*512
                             + (size_t)((col&15) + (((i>>3)&3)<<4))*8 + (i&7);
                    v_f[o] = f2bf(s);
                } else {
                    gate[(size_t)row*HID + (col - HID)] = s;
                }
            }
        }
    }
}

// ---------- K3: Z = silu(bf16(n) @ (Wqk_hi+Wqk_lo) + bqk); q,k bf16 frag-major ----------
// q_f/k_f: [it=row>>4][ks=col>>5][512]   lane=(row&15)+16*((col>>3)&3), e=col&7
__global__ __launch_bounds__(256,2) void gemm_qk(
        const u16* __restrict__ nh,
        const u16* __restrict__ bth, const u16* __restrict__ btl,
        const float* __restrict__ bqk, const float* __restrict__ gamma,
        const float* __restrict__ beta,
        u16* q_f, u16* k_f){
    __shared__ __align__(16) u16 At[128][40];
    __shared__ __align__(16) u16 Bt[2][128][40];
    int m0 = blockIdx.x * 128;
    int wave = threadIdx.x>>6, lane = threadIdx.x&63;
    int wr = wave>>1, wc = wave&1;
    f32x4 acc[4][4] = {};
    for (int ks=0; ks<16; ++ks){
        #pragma unroll
        for (int r=0;r<2;++r){
            int idx = r*256 + threadIdx.x;
            int row = idx>>2, ch = idx&3;
            size_t ga = (size_t)(m0+row)*DIM + ks*32 + ch*8;
            size_t gb = (size_t)row*DIM + ks*32 + ch*8;   // n0 = 0, N=128
            *(uint4*)&At[row][ch*8]    = *(const uint4*)(nh + ga);
            *(uint4*)&Bt[0][row][ch*8] = *(const uint4*)(bth + gb);
            *(uint4*)&Bt[1][row][ch*8] = *(const uint4*)(btl + gb);
        }
        __syncthreads();
        bf16x8 Ah[4];
        #pragma unroll
        for (int rf=0;rf<4;++rf)
            Ah[rf] = ld_frag(&At[wr*64 + rf*16 + (lane&15)][(lane>>4)*8]);
        #pragma unroll
        for (int cf=0;cf<4;++cf){
            bf16x8 Bh = ld_frag(&Bt[0][wc*64 + cf*16 + (lane&15)][(lane>>4)*8]);
            bf16x8 Bl = ld_frag(&Bt[1][wc*64 + cf*16 + (lane&15)][(lane>>4)*8]);
            #pragma unroll
            for (int rf=0;rf<4;++rf){
                acc[rf][cf] = mfma16(Ah[rf], Bh, acc[rf][cf]);
                acc[rf][cf] = mfma16(Ah[rf], Bl, acc[rf][cf]);
            }
        }
        __syncthreads();
    }
    #pragma unroll
    for (int rf=0;rf<4;++rf){
        #pragma unroll
        for (int cf=0;cf<4;++cf){
            #pragma unroll
            for (int r=0;r<4;++r){
                int row = m0 + wr*64 + rf*16 + (lane>>4)*4 + r;
                int col = wc*64 + cf*16 + (lane&15);
                float z = silu(acc[rf][cf][r] + bqk[col]);
                float qv = z*gamma[col]       + beta[col];
                float kv = z*gamma[QKD + col] + beta[QKD + col];
                size_t lane_e = (size_t)((row&15) + (((col>>3)&3)<<4))*8 + (col&7);
                size_t it4ks  = (size_t)(row>>4)*4 + (col>>5);
                q_f[it4ks*512 + lane_e] = f2bf(qv);
                k_f[it4ks*512 + lane_e] = f2bf(kv);
            }
        }
    }
}

// ---------- K4: fused squared-relu attention ----------
// grid = 256 blocks (1/CU): xcd=bid&7 -> (batch, dhalf), qt=bid>>3. 1024 thr, 16 waves.
// QTILE=128, KV=64, d-slice 512/block.
// QK decomposition: wave = (fr=w>>1: 16q strip, fc=w&1: 32j half). Q frags persistent
// in registers (no LDS). K staged via global_load_lds dbuf (2x16KB), prefetch 1 ahead.
// PV decomposition: wave = (qh=w>>3: 64q half, ds=w&7: 64d slice) -> A-tile LDS reads
// halve vs round 7 (8KB/wave). V direct global->reg, kk0 issued at kt top (latency
// covered by QK+pack before the barrier's vmcnt(0) drain). ONE barrier per kt.
__global__ __launch_bounds__(1024,4) void attn(
        const u16* __restrict__ q_f, const u16* __restrict__ k_f,
        const u16* __restrict__ v_f, float* gate){
    __shared__ __align__(16) u16 KT[2][8192];    // dbuf: 64j x 128dim frag-major
    __shared__ __align__(16) u16 AT[2][128*72];  // dbuf: A = relu(S)^2, pitch 72
    const int bid = blockIdx.x, xcd = bid & 7;
    const int batch = xcd >> 1, dhalf = xcd & 1, qt = bid >> 3;
    const int i0 = qt * 128;
    const int w = threadIdx.x >> 6, lane = threadIdx.x & 63;
    const int fr = w >> 1, fc = w & 1;    // QK: 16q x 32j
    const int qh = w >> 3, ds = w & 7;    // PV: 64q half x 64d slice

    // ---- persistent Q fragments (A-operand) for this wave's q-strip ----
    bf16x8 qf[4];
    {
        int itq = batch*256 + qt*8 + fr;       // SEQ/16 = 256 it-tiles per batch
        #pragma unroll
        for (int ks=0;ks<4;++ks)
            qf[ks] = ld_frag(q_f + ((size_t)itq*4 + ks)*512 + lane*8);
    }
    // ---- K staging: 16KB per kt, 16 waves x 1KB, async ----
    auto stageK = [&](int kt, int p){
        size_t kbase = ((size_t)(batch*256 + kt*4))*2048;
        gload_lds16(k_f + kbase + (size_t)w*512 + lane*8, &KT[p][w*512]);
    };
    stageK(0, 0);
    __syncthreads();

    f32x4 acc[4][4] = {};   // 64q(half) x 64d(slice) per wave
    for (int kt=0; kt<64; ++kt){
        const int p = kt & 1;
        stageK((kt+1)&63, p^1);   // prefetch next K tile
        // ---- V kk0 frags: issue at top, full QK+pack coverage ----
        bf16x8 vb0[4];
        #pragma unroll
        for (int dc=0;dc<4;++dc)
            vb0[dc] = ld_frag(v_f + (((size_t)(batch*128 + kt*2))*64
                              + dhalf*32 + ds*4 + dc)*512 + lane*8);
        // ---- QK: S = q.k^T, wave does 16q x 32j ----
        f32x4 sacc[2] = {};
        #pragma unroll
        for (int t=0;t<2;++t){
            #pragma unroll
            for (int ks=0;ks<4;++ks){
                bf16x8 kb = ld_frag(&KT[p][((fc*2 + t)*4 + ks)*512 + lane*8]);
                sacc[t] = mfma16(qf[ks], kb, sacc[t]);
            }
        }
        // ---- V kk1 frags (partial coverage before barrier) ----
        bf16x8 vb1[4];
        #pragma unroll
        for (int dc=0;dc<4;++dc)
            vb1[dc] = ld_frag(v_f + (((size_t)(batch*128 + kt*2 + 1))*64
                              + dhalf*32 + ds*4 + dc)*512 + lane*8);
        // ---- A = bf16(relu(S)^2) -> LDS (pitch 72, dbuf) ----
        u16* Ab = AT[p];
        #pragma unroll
        for (int t=0;t<2;++t){
            #pragma unroll
            for (int r=0;r<4;++r){
                float s = sacc[t][r];
                s = s > 0.f ? s*s : 0.f;
                int q = fr*16 + (lane>>4)*4 + r;
                int j = fc*32 + t*16 + (lane&15);
                Ab[q*72 + j] = f2bf(s);
            }
        }
        __syncthreads();   // A visible; K(kt+1) + V drained
        // ---- PV: acc += A @ v on wave's (64q half, 64d slice) ----
        #pragma unroll
        for (int qr=0;qr<4;++qr){
            bf16x8 af0 = ld_frag(&Ab[(qh*64 + qr*16 + (lane&15))*72 + (lane>>4)*8]);
            #pragma unroll
            for (int dc=0;dc<4;++dc)
                acc[qr][dc] = mfma16(af0, vb0[dc], acc[qr][dc]);
            bf16x8 af1 = ld_frag(&Ab[(qh*64 + qr*16 + (lane&15))*72 + 32 + (lane>>4)*8]);
            #pragma unroll
            for (int dc=0;dc<4;++dc)
                acc[qr][dc] = mfma16(af1, vb1[dc], acc[qr][dc]);
        }
    }
    // ---- epilogue: gate <- V * gate * 2^-24 ----
    #pragma unroll
    for (int qr=0; qr<4; ++qr){
        #pragma unroll
        for (int dc=0; dc<4; ++dc){
            #pragma unroll
            for (int r=0; r<4; ++r){
                int i = i0 + qh*64 + qr*16 + (lane>>4)*4 + r;
                int d = dhalf*512 + ds*64 + dc*16 + (lane&15);
                size_t go = ((size_t)(batch*SEQ + i))*HID + d;
                float g = gate[go];
                gate[go] = acc[qr][dc][r] * g * 0x1p-24f;
            }
        }
    }
}

// ---------- K5: out = Vg @ Wo + bo ----------
__global__ __launch_bounds__(256) void wo_kernel(const float* __restrict__ vg,
                                                 const float* __restrict__ Wo,
                                                 const float* __restrict__ bo,
                                                 float* out){
    int wave = threadIdx.x>>6, lane = threadIdx.x&63;
    int row  = blockIdx.x*4 + wave;
    const float* vr = vg + (size_t)row*HID;
    float po[8] = {};
    #pragma unroll
    for (int c=0;c<4;++c){
        float4 v = *(const float4*)(vr + c*256 + lane*4);
        float vv[4] = {v.x, v.y, v.z, v.w};
        #pragma unroll
        for (int e=0;e<4;++e){
            int col = c*256 + lane*4 + e;
            float4 w0 = *(const float4*)(Wo + (size_t)col*8);
            float4 w1 = *(const float4*)(Wo + (size_t)col*8 + 4);
            po[0] += vv[e]*w0.x; po[1] += vv[e]*w0.y; po[2] += vv[e]*w0.z; po[3] += vv[e]*w0.w;
            po[4] += vv[e]*w1.x; po[5] += vv[e]*w1.y; po[6] += vv[e]*w1.z; po[7] += vv[e]*w1.w;
        }
    }
    #pragma unroll
    for (int m=1;m<64;m<<=1){
        #pragma unroll
        for (int o=0;o<8;++o) po[o] += __shfl_xor(po[o], m, 64);
    }
    if (lane == 0){
        #pragma unroll
        for (int o=0;o<8;++o) out[(size_t)row*8 + o] = po[o] + bo[o];
    }
}

// ---------- launch ----------
extern "C" void kernel_launch(void* const* d_in, const int* in_sizes, int n_in,
                              void* d_out, int out_size, void* d_ws, size_t ws_size,
                              hipStream_t stream){
    const float* x    = (const float*)d_in[0];
    const float* ln_g = (const float*)d_in[1];
    const float* ln_b = (const float*)d_in[2];
    const float* Wh   = (const float*)d_in[3];
    const float* bh   = (const float*)d_in[4];
    const float* Wqk  = (const float*)d_in[5];
    const float* bqk  = (const float*)d_in[6];
    const float* gamma= (const float*)d_in[7];
    const float* beta = (const float*)d_in[8];
    const float* Wo   = (const float*)d_in[9];
    const float* bo   = (const float*)d_in[10];
    float* out = (float*)d_out;

    char* w = (char*)d_ws;
    auto alloc = [&](size_t bytes)->char*{
        char* p = w; w += (bytes + 255) & ~(size_t)255; return p;
    };
    u16* nh    = (u16*)alloc((size_t)ROWS*DIM*2);
    u16* whth  = (u16*)alloc((size_t)HID2*DIM*2);
    u16* whtl  = (u16*)alloc((size_t)HID2*DIM*2);
    u16* wqkth = (u16*)alloc((size_t)QKD*DIM*2);
    u16* wqktl = (u16*)alloc((size_t)QKD*DIM*2);
    u16* q_f   = (u16*)alloc((size_t)ROWS*QKD*2);      // bf16, fragment-major
    u16* k_f   = (u16*)alloc((size_t)ROWS*QKD*2);      // bf16, fragment-major
    u16* v_f   = (u16*)alloc((size_t)BATCH*HID*SEQ*2); // bf16, fragment-major
    float* gate= (float*)alloc((size_t)ROWS*HID*4);

    prep_split<<<(HID2*DIM + QKD*DIM)/256, 256, 0, stream>>>(Wh, Wqk, whth, whtl, wqkth, wqktl);
    ln_kernel<<<ROWS/4, 256, 0, stream>>>(x, ln_g, ln_b, nh);
    gemm_h<<<dim3(HID2/128, ROWS/128), 256, 0, stream>>>(nh, whth, whtl, bh, v_f, gate);
    gemm_qk<<<ROWS/128, 256, 0, stream>>>(nh, wqkth, wqktl, bqk, gamma, beta, q_f, k_f);
    attn<<<256, 1024, 0, stream>>>(q_f, k_f, v_f, gate);
    wo_kernel<<<ROWS/4, 256, 0, stream>>>(gate, Wo, bo, out);
}

// Round 9
// 358.682 us; speedup vs baseline: 2.9313x; 1.0194x over previous
//
#include <hip/hip_runtime.h>
#include <stdint.h>

#define DIM   512
#define QKD   128
#define HID   1024
#define HID2  2048
#define OUTD  8
#define BATCH 4
#define SEQ   4096
#define ROWS  (BATCH*SEQ)   // 16384
#define LN_EPS 1e-5f

typedef unsigned short u16;
typedef unsigned int   u32;
typedef __bf16 bf16x8 __attribute__((ext_vector_type(8)));
typedef float  f32x4  __attribute__((ext_vector_type(4)));

// ---------- helpers ----------
__device__ inline u16 f2bf(float f){
    uint32_t u = __builtin_bit_cast(uint32_t, f);
    u += 0x7FFFu + ((u >> 16) & 1u);   // RNE
    return (u16)(u >> 16);
}
__device__ inline float bf2f(u16 h){
    uint32_t u = ((uint32_t)h) << 16;
    return __builtin_bit_cast(float, u);
}
__device__ inline void split_bf16(float x, u16 &hi, u16 &lo){
    hi = f2bf(x);
    float r = x - bf2f(hi);
    lo = f2bf(r);
}
__device__ inline bf16x8 ld_frag(const u16* p){
    uint4 r = *reinterpret_cast<const uint4*>(p);
    return __builtin_bit_cast(bf16x8, r);
}
__device__ inline f32x4 mfma16(bf16x8 a, bf16x8 b, f32x4 c){
    return __builtin_amdgcn_mfma_f32_16x16x32_bf16(a, b, c, 0, 0, 0);
}
__device__ inline float silu(float x){ return x / (1.f + expf(-x)); }
// async global->LDS: PER-LANE global src addr, wave-uniform LDS base (+lane*16B)
__device__ inline void gload_lds16(const u16* g, u16* l){
    __builtin_amdgcn_global_load_lds(
        (const __attribute__((address_space(1))) u32*)g,
        (__attribute__((address_space(3))) u32*)l, 16, 0, 0);
}

// ---------- P: split + transpose weights ----------
__global__ void prep_split(const float* __restrict__ Wh, const float* __restrict__ Wqk,
                           u16* whth, u16* whtl, u16* wqkth, u16* wqktl){
    int tid = blockIdx.x*256 + threadIdx.x;
    const int NWH = HID2*DIM;            // 1048576
    if (tid < NWH){
        int k = tid & (DIM-1);
        int n = tid >> 9;
        float w = Wh[(size_t)k*HID2 + n];
        u16 h,l; split_bf16(w,h,l);
        whth[tid]=h; whtl[tid]=l;
    } else {
        int t2 = tid - NWH;
        if (t2 < QKD*DIM){
            int k = t2 & (DIM-1);
            int n = t2 >> 9;
            float w = Wqk[(size_t)k*QKD + n];
            u16 h,l; split_bf16(w,h,l);
            wqkth[t2]=h; wqktl[t2]=l;
        }
    }
}

// ---------- K1: layernorm -> bf16 ----------
__global__ __launch_bounds__(256) void ln_kernel(const float* __restrict__ x,
                                                 const float* __restrict__ g,
                                                 const float* __restrict__ b,
                                                 u16* nh){
    int wave = threadIdx.x >> 6, lane = threadIdx.x & 63;
    int row  = blockIdx.x*4 + wave;
    const float* xr = x + (size_t)row*DIM;
    float4 v0 = *(const float4*)(xr + lane*8);
    float4 v1 = *(const float4*)(xr + lane*8 + 4);
    float xs[8] = {v0.x,v0.y,v0.z,v0.w,v1.x,v1.y,v1.z,v1.w};
    float s = 0.f, q = 0.f;
    #pragma unroll
    for (int i=0;i<8;++i){ s += xs[i]; q += xs[i]*xs[i]; }
    #pragma unroll
    for (int m=1;m<64;m<<=1){ s += __shfl_xor(s,m,64); q += __shfl_xor(q,m,64); }
    float mean = s * (1.f/DIM);
    float var  = q * (1.f/DIM) - mean*mean;
    float rstd = rsqrtf(var + LN_EPS);
    float4 g0 = *(const float4*)(g + lane*8);
    float4 g1 = *(const float4*)(g + lane*8 + 4);
    float4 b0 = *(const float4*)(b + lane*8);
    float4 b1 = *(const float4*)(b + lane*8 + 4);
    float gs[8] = {g0.x,g0.y,g0.z,g0.w,g1.x,g1.y,g1.z,g1.w};
    float bs[8] = {b0.x,b0.y,b0.z,b0.w,b1.x,b1.y,b1.z,b1.w};
    u16 hh[8];
    #pragma unroll
    for (int i=0;i<8;++i){
        float nv = (xs[i]-mean)*rstd*gs[i] + bs[i];
        hh[i] = f2bf(nv);
    }
    size_t o = (size_t)row*DIM + lane*8;
    *(uint4*)(nh + o) = *(uint4*)hh;
}

// ---------- K2: hidden = silu(bf16(n) @ (Wh_hi+Wh_lo) + bh) -> v_f + gate ----------
// m97 structure: 3 tiles staged via global_load_lds (linear LDS), dbuf, 1 barrier/ks.
// grid 2048 linear, XCD swizzle: 2 n-panels per XCD (B tiles L2-resident).
__global__ __launch_bounds__(256,2) void gemm_h(
        const u16* __restrict__ nh,
        const u16* __restrict__ bth, const u16* __restrict__ btl,
        const float* __restrict__ bh,
        u16* v_f, float* gate){
    __shared__ __align__(16) u16 SA [2][128*32];
    __shared__ __align__(16) u16 SB0[2][128*32];
    __shared__ __align__(16) u16 SB1[2][128*32];
    const int bid = blockIdx.x;
    const int xcd = bid & 7, bx = bid >> 3;
    const int nb = xcd*2 + (bx >> 7);    // 0..15
    const int mb = bx & 127;             // 0..127
    const int n0 = nb*128, m0 = mb*128;
    const int w = threadIdx.x >> 6, lane = threadIdx.x & 63;
    const int wr = w >> 1, wc = w & 1;

    auto stage = [&](int ks, int p){
        #pragma unroll
        for (int c=0;c<2;++c){
            int row = w*32 + c*16 + (lane>>2);       // 0..127
            const u16* gA = nh  + (size_t)(m0+row)*DIM + ks*32 + (lane&3)*8;
            const u16* gB0= bth + (size_t)(n0+row)*DIM + ks*32 + (lane&3)*8;
            const u16* gB1= btl + (size_t)(n0+row)*DIM + ks*32 + (lane&3)*8;
            int off = w*1024 + c*512;                // u16 elems, wave-uniform
            gload_lds16(gA , &SA [p][off]);
            gload_lds16(gB0, &SB0[p][off]);
            gload_lds16(gB1, &SB1[p][off]);
        }
    };

    stage(0, 0);
    __syncthreads();

    f32x4 acc[4][4] = {};
    for (int ks=0; ks<16; ++ks){
        const int p = ks & 1;
        if (ks < 15) stage(ks+1, p^1);
        bf16x8 Ah[4];
        #pragma unroll
        for (int rf=0;rf<4;++rf)
            Ah[rf] = ld_frag(&SA[p][(wr*64 + rf*16 + (lane&15))*32 + (lane>>4)*8]);
        #pragma unroll
        for (int cf=0;cf<4;++cf){
            bf16x8 Bh = ld_frag(&SB0[p][(wc*64 + cf*16 + (lane&15))*32 + (lane>>4)*8]);
            bf16x8 Bl = ld_frag(&SB1[p][(wc*64 + cf*16 + (lane&15))*32 + (lane>>4)*8]);
            #pragma unroll
            for (int rf=0;rf<4;++rf){
                acc[rf][cf] = mfma16(Ah[rf], Bh, acc[rf][cf]);
                acc[rf][cf] = mfma16(Ah[rf], Bl, acc[rf][cf]);
            }
        }
        __syncthreads();
    }
    #pragma unroll
    for (int rf=0;rf<4;++rf){
        #pragma unroll
        for (int cf=0;cf<4;++cf){
            #pragma unroll
            for (int r=0;r<4;++r){
                int row = m0 + wr*64 + rf*16 + (lane>>4)*4 + r;
                int col = n0 + wc*64 + cf*16 + (lane&15);
                float h = acc[rf][cf][r] + bh[col];
                float s = silu(h);
                if (col < HID){
                    int b = row >> 12, i = row & (SEQ-1);
                    size_t o = (((size_t)b*128 + (i>>5))*64 + (col>>4))*512
                             + (size_t)((col&15) + (((i>>3)&3)<<4))*8 + (i&7);
                    v_f[o] = f2bf(s);
                } else {
                    gate[(size_t)row*HID + (col - HID)] = s;
                }
            }
        }
    }
}

// ---------- K3: Z = silu(bf16(n) @ (Wqk_hi+Wqk_lo) + bqk); q,k bf16 frag-major ----------
// q_f/k_f: [it=row>>4][ks=col>>5][512]   lane=(row&15)+16*((col>>3)&3), e=col&7
__global__ __launch_bounds__(256,2) void gemm_qk(
        const u16* __restrict__ nh,
        const u16* __restrict__ bth, const u16* __restrict__ btl,
        const float* __restrict__ bqk, const float* __restrict__ gamma,
        const float* __restrict__ beta,
        u16* q_f, u16* k_f){
    __shared__ __align__(16) u16 At[128][40];
    __shared__ __align__(16) u16 Bt[2][128][40];
    int m0 = blockIdx.x * 128;
    int wave = threadIdx.x>>6, lane = threadIdx.x&63;
    int wr = wave>>1, wc = wave&1;
    f32x4 acc[4][4] = {};
    for (int ks=0; ks<16; ++ks){
        #pragma unroll
        for (int r=0;r<2;++r){
            int idx = r*256 + threadIdx.x;
            int row = idx>>2, ch = idx&3;
            size_t ga = (size_t)(m0+row)*DIM + ks*32 + ch*8;
            size_t gb = (size_t)row*DIM + ks*32 + ch*8;   // n0 = 0, N=128
            *(uint4*)&At[row][ch*8]    = *(const uint4*)(nh + ga);
            *(uint4*)&Bt[0][row][ch*8] = *(const uint4*)(bth + gb);
            *(uint4*)&Bt[1][row][ch*8] = *(const uint4*)(btl + gb);
        }
        __syncthreads();
        bf16x8 Ah[4];
        #pragma unroll
        for (int rf=0;rf<4;++rf)
            Ah[rf] = ld_frag(&At[wr*64 + rf*16 + (lane&15)][(lane>>4)*8]);
        #pragma unroll
        for (int cf=0;cf<4;++cf){
            bf16x8 Bh = ld_frag(&Bt[0][wc*64 + cf*16 + (lane&15)][(lane>>4)*8]);
            bf16x8 Bl = ld_frag(&Bt[1][wc*64 + cf*16 + (lane&15)][(lane>>4)*8]);
            #pragma unroll
            for (int rf=0;rf<4;++rf){
                acc[rf][cf] = mfma16(Ah[rf], Bh, acc[rf][cf]);
                acc[rf][cf] = mfma16(Ah[rf], Bl, acc[rf][cf]);
            }
        }
        __syncthreads();
    }
    #pragma unroll
    for (int rf=0;rf<4;++rf){
        #pragma unroll
        for (int cf=0;cf<4;++cf){
            #pragma unroll
            for (int r=0;r<4;++r){
                int row = m0 + wr*64 + rf*16 + (lane>>4)*4 + r;
                int col = wc*64 + cf*16 + (lane&15);
                float z = silu(acc[rf][cf][r] + bqk[col]);
                float qv = z*gamma[col]       + beta[col];
                float kv = z*gamma[QKD + col] + beta[QKD + col];
                size_t lane_e = (size_t)((row&15) + (((col>>3)&3)<<4))*8 + (col&7);
                size_t it4ks  = (size_t)(row>>4)*4 + (col>>5);
                q_f[it4ks*512 + lane_e] = f2bf(qv);
                k_f[it4ks*512 + lane_e] = f2bf(kv);
            }
        }
    }
}

// ---------- K4: fused squared-relu attention ----------
// grid = 512 blocks (2/CU), 512 threads, 8 waves. xcd=bid&7 -> (batch,dhalf);
// qt=bid>>3 (0..63), QTILE=64, KV=64, d-slice 512/block.
// Q staged once in LDS (16KB). K via global_load_lds dbuf (2x16KB), prefetch 1 ahead.
// QK: wave = (fr=w>>1: 16q strip, fc=w&1: 32j half). PV: wave = ds=w (64d slice) ->
// V read EXACTLY once (dup 1), direct global->reg, kk-chunked to cap liveness.
// A via LDS pitch 72, dbuf. ONE barrier per kt; second CU-resident block fills stalls.
__global__ __launch_bounds__(512,4) void attn(
        const u16* __restrict__ q_f, const u16* __restrict__ k_f,
        const u16* __restrict__ v_f, float* gate){
    __shared__ __align__(16) u16 QL[8192];       // 64q x 128d frag-major (4 it-tiles)
    __shared__ __align__(16) u16 KT[2][8192];    // dbuf: 64j x 128d frag-major
    __shared__ __align__(16) u16 AT[2][64*72];   // dbuf: A = relu(S)^2, pitch 72
    const int bid = blockIdx.x, xcd = bid & 7;
    const int batch = xcd >> 1, dhalf = xcd & 1, qt = bid >> 3;
    const int i0 = qt * 64;
    const int w = threadIdx.x >> 6, lane = threadIdx.x & 63;
    const int fr = w >> 1, fc = w & 1;    // QK: 16q strip x 32j half
    const int ds = w;                     // PV: 64d slice

    // ---- stage Q once + K(0), async ----
    {
        size_t qbase = ((size_t)(batch*256 + qt*4))*2048;
        size_t kbase = ((size_t)(batch*256 + 0*4))*2048;
        #pragma unroll
        for (int c=0;c<2;++c){
            int off = w*1024 + c*512;
            gload_lds16(q_f + qbase + off + lane*8, &QL[off]);
            gload_lds16(k_f + kbase + off + lane*8, &KT[0][off]);
        }
    }
    __syncthreads();

    f32x4 acc[4][4] = {};   // 64q x 64d per wave
    for (int kt=0; kt<64; ++kt){
        const int p = kt & 1;
        // prefetch K(kt+1) -> other buffer (drains at this kt's barrier)
        {
            size_t kbase = ((size_t)(batch*256 + (((kt+1)&63))*4))*2048;
            #pragma unroll
            for (int c=0;c<2;++c){
                int off = w*1024 + c*512;
                gload_lds16(k_f + kbase + off + lane*8, &KT[p^1][off]);
            }
        }
        // V kk0 frags (consumed after barrier; latency covered by QK+pack)
        bf16x8 vb0[4];
        #pragma unroll
        for (int dc=0;dc<4;++dc)
            vb0[dc] = ld_frag(v_f + (((size_t)(batch*128 + kt*2))*64
                              + dhalf*32 + ds*4 + dc)*512 + lane*8);
        // ---- QK: S = q.k^T, wave does 16q x 32j ----
        f32x4 sacc[2] = {};
        #pragma unroll
        for (int ks=0;ks<4;++ks){
            bf16x8 qa = ld_frag(&QL[fr*2048 + ks*512 + lane*8]);
            #pragma unroll
            for (int t=0;t<2;++t){
                bf16x8 kb = ld_frag(&KT[p][(fc*2 + t)*2048 + ks*512 + lane*8]);
                sacc[t] = mfma16(qa, kb, sacc[t]);
            }
        }
        // ---- A = bf16(relu(S)^2) -> LDS (pitch 72, dbuf) ----
        u16* Ab = AT[p];
        #pragma unroll
        for (int t=0;t<2;++t){
            #pragma unroll
            for (int r=0;r<4;++r){
                float s = sacc[t][r];
                s = s > 0.f ? s*s : 0.f;
                int q = fr*16 + (lane>>4)*4 + r;
                int j = fc*32 + t*16 + (lane&15);
                Ab[q*72 + j] = f2bf(s);
            }
        }
        __syncthreads();   // A visible; K(kt+1) + vb0 drained
        // ---- PV kk0 ----
        #pragma unroll
        for (int qr=0;qr<4;++qr){
            bf16x8 af = ld_frag(&Ab[(qr*16 + (lane&15))*72 + (lane>>4)*8]);
            #pragma unroll
            for (int dc=0;dc<4;++dc)
                acc[qr][dc] = mfma16(af, vb0[dc], acc[qr][dc]);
        }
        // ---- V kk1 (vb0 regs dead -> reuse pressure; latency covered by kk1 A-reads) ----
        bf16x8 vb1[4];
        #pragma unroll
        for (int dc=0;dc<4;++dc)
            vb1[dc] = ld_frag(v_f + (((size_t)(batch*128 + kt*2 + 1))*64
                              + dhalf*32 + ds*4 + dc)*512 + lane*8);
        // ---- PV kk1 ----
        #pragma unroll
        for (int qr=0;qr<4;++qr){
            bf16x8 af = ld_frag(&Ab[(qr*16 + (lane&15))*72 + 32 + (lane>>4)*8]);
            #pragma unroll
            for (int dc=0;dc<4;++dc)
                acc[qr][dc] = mfma16(af, vb1[dc], acc[qr][dc]);
        }
    }
    // ---- epilogue: gate <- V * gate * 2^-24 ----
    #pragma unroll
    for (int qr=0; qr<4; ++qr){
        #pragma unroll
        for (int dc=0; dc<4; ++dc){
            #pragma unroll
            for (int r=0; r<4; ++r){
                int i = i0 + qr*16 + (lane>>4)*4 + r;
                int d = dhalf*512 + ds*64 + dc*16 + (lane&15);
                size_t go = ((size_t)(batch*SEQ + i))*HID + d;
                float g = gate[go];
                gate[go] = acc[qr][dc][r] * g * 0x1p-24f;
            }
        }
    }
}

// ---------- K5: out = Vg @ Wo + bo ----------
__global__ __launch_bounds__(256) void wo_kernel(const float* __restrict__ vg,
                                                 const float* __restrict__ Wo,
                                                 const float* __restrict__ bo,
                                                 float* out){
    int wave = threadIdx.x>>6, lane = threadIdx.x&63;
    int row  = blockIdx.x*4 + wave;
    const float* vr = vg + (size_t)row*HID;
    float po[8] = {};
    #pragma unroll
    for (int c=0;c<4;++c){
        float4 v = *(const float4*)(vr + c*256 + lane*4);
        float vv[4] = {v.x, v.y, v.z, v.w};
        #pragma unroll
        for (int e=0;e<4;++e){
            int col = c*256 + lane*4 + e;
            float4 w0 = *(const float4*)(Wo + (size_t)col*8);
            float4 w1 = *(const float4*)(Wo + (size_t)col*8 + 4);
            po[0] += vv[e]*w0.x; po[1] += vv[e]*w0.y; po[2] += vv[e]*w0.z; po[3] += vv[e]*w0.w;
            po[4] += vv[e]*w1.x; po[5] += vv[e]*w1.y; po[6] += vv[e]*w1.z; po[7] += vv[e]*w1.w;
        }
    }
    #pragma unroll
    for (int m=1;m<64;m<<=1){
        #pragma unroll
        for (int o=0;o<8;++o) po[o] += __shfl_xor(po[o], m, 64);
    }
    if (lane == 0){
        #pragma unroll
        for (int o=0;o<8;++o) out[(size_t)row*8 + o] = po[o] + bo[o];
    }
}

// ---------- launch ----------
extern "C" void kernel_launch(void* const* d_in, const int* in_sizes, int n_in,
                              void* d_out, int out_size, void* d_ws, size_t ws_size,
                              hipStream_t stream){
    const float* x    = (const float*)d_in[0];
    const float* ln_g = (const float*)d_in[1];
    const float* ln_b = (const float*)d_in[2];
    const float* Wh   = (const float*)d_in[3];
    const float* bh   = (const float*)d_in[4];
    const float* Wqk  = (const float*)d_in[5];
    const float* bqk  = (const float*)d_in[6];
    const float* gamma= (const float*)d_in[7];
    const float* beta = (const float*)d_in[8];
    const float* Wo   = (const float*)d_in[9];
    const float* bo   = (const float*)d_in[10];
    float* out = (float*)d_out;

    char* w = (char*)d_ws;
    auto alloc = [&](size_t bytes)->char*{
        char* p = w; w += (bytes + 255) & ~(size_t)255; return p;
    };
    u16* nh    = (u16*)alloc((size_t)ROWS*DIM*2);
    u16* whth  = (u16*)alloc((size_t)HID2*DIM*2);
    u16* whtl  = (u16*)alloc((size_t)HID2*DIM*2);
    u16* wqkth = (u16*)alloc((size_t)QKD*DIM*2);
    u16* wqktl = (u16*)alloc((size_t)QKD*DIM*2);
    u16* q_f   = (u16*)alloc((size_t)ROWS*QKD*2);      // bf16, fragment-major
    u16* k_f   = (u16*)alloc((size_t)ROWS*QKD*2);      // bf16, fragment-major
    u16* v_f   = (u16*)alloc((size_t)BATCH*HID*SEQ*2); // bf16, fragment-major
    float* gate= (float*)alloc((size_t)ROWS*HID*4);

    prep_split<<<(HID2*DIM + QKD*DIM)/256, 256, 0, stream>>>(Wh, Wqk, whth, whtl, wqkth, wqktl);
    ln_kernel<<<ROWS/4, 256, 0, stream>>>(x, ln_g, ln_b, nh);
    gemm_h<<<2048, 256, 0, stream>>>(nh, whth, whtl, bh, v_f, gate);
    gemm_qk<<<ROWS/128, 256, 0, stream>>>(nh, wqkth, wqktl, bqk, gamma, beta, q_f, k_f);
    attn<<<512, 512, 0, stream>>>(q_f, k_f, v_f, gate);
    wo_kernel<<<ROWS/4, 256, 0, stream>>>(gate, Wo, bo, out);
}